// Round 2
// baseline (10724.527 us; speedup 1.0000x reference)
//
#include <hip/hip_runtime.h>

static constexpr int D = 96;      // hidden size
static constexpr int NSTEPS = 4;  // GGNN propagation steps

// Y[i, c] = sum_k X[i,k] * W[c,k] + b[c]   (X: [n,D], W: [M,D] row-major)
__global__ void node_linear_kernel(const float* __restrict__ X,
                                   const float* __restrict__ W,
                                   const float* __restrict__ b,
                                   float* __restrict__ Y,
                                   int n, int M) {
  int idx = blockIdx.x * blockDim.x + threadIdx.x;
  if (idx >= n * M) return;
  int i = idx / M;
  int c = idx - i * M;
  const float* xr = X + (long long)i * D;
  const float* wr = W + (long long)c * D;
  float acc = b[c];
#pragma unroll 8
  for (int k = 0; k < D; ++k) acc += xr[k] * wr[k];
  Y[idx] = acc;
}

// a[dst[e], d] += m[src[e], d]
__global__ void scatter_add_kernel(const float* __restrict__ m,
                                   const int* __restrict__ src,
                                   const int* __restrict__ dst,
                                   float* __restrict__ a, int E) {
  long long idx = (long long)blockIdx.x * blockDim.x + threadIdx.x;
  long long total = (long long)E * D;
  if (idx >= total) return;
  int e = (int)(idx / D);
  int d = (int)(idx - (long long)e * D);
  int s = src[e];
  int t = dst[e];
  atomicAdd(&a[(long long)t * D + d], m[(long long)s * D + d]);
}

// Fused GRUCell: hout[i,d] = (1-z)*n + z*h[i,d], gate order r,z,n (torch layout)
__global__ void gru_kernel(const float* __restrict__ a,
                           const float* __restrict__ h,
                           float* __restrict__ hout,
                           const float* __restrict__ Wih,
                           const float* __restrict__ Whh,
                           const float* __restrict__ bih,
                           const float* __restrict__ bhh,
                           int n) {
  int idx = blockIdx.x * blockDim.x + threadIdx.x;
  if (idx >= n * D) return;
  int i = idx / D;
  int d = idx - i * D;
  const float* ar = a + (long long)i * D;
  const float* hr = h + (long long)i * D;
  const float* wi_r = Wih + (long long)d * D;
  const float* wi_z = Wih + (long long)(D + d) * D;
  const float* wi_n = Wih + (long long)(2 * D + d) * D;
  const float* wh_r = Whh + (long long)d * D;
  const float* wh_z = Whh + (long long)(D + d) * D;
  const float* wh_n = Whh + (long long)(2 * D + d) * D;
  float accr = bih[d] + bhh[d];
  float accz = bih[D + d] + bhh[D + d];
  float accxn = bih[2 * D + d];
  float acchn = bhh[2 * D + d];
#pragma unroll 4
  for (int k = 0; k < D; ++k) {
    float ak = ar[k];
    float hk = hr[k];
    accr  += ak * wi_r[k] + hk * wh_r[k];
    accz  += ak * wi_z[k] + hk * wh_z[k];
    accxn += ak * wi_n[k];
    acchn += hk * wh_n[k];
  }
  float r = 1.0f / (1.0f + __expf(-accr));
  float z = 1.0f / (1.0f + __expf(-accz));
  float nn = tanhf(accxn + r * acchn);
  hout[idx] = (1.0f - z) * nn + z * hr[d];
}

// logits[i,c] = sum_k elu(h[i,k]) * Wfc[c,k] + bfc[c]
__global__ void head_kernel(const float* __restrict__ h,
                            const float* __restrict__ Wfc,
                            const float* __restrict__ bfc,
                            float* __restrict__ out,
                            int n, int C) {
  int idx = blockIdx.x * blockDim.x + threadIdx.x;
  if (idx >= n * C) return;
  int i = idx / C;
  int c = idx - i * C;
  const float* hr = h + (long long)i * D;
  const float* wr = Wfc + (long long)c * D;
  float acc = bfc[c];
#pragma unroll 8
  for (int k = 0; k < D; ++k) {
    float hv = hr[k];
    float e = hv > 0.0f ? hv : (__expf(hv) - 1.0f);
    acc += e * wr[k];
  }
  out[idx] = acc;
}

extern "C" void kernel_launch(void* const* d_in, const int* in_sizes, int n_in,
                              void* d_out, int out_size, void* d_ws, size_t ws_size,
                              hipStream_t stream) {
  const float* x    = (const float*)d_in[0];
  const int*   src  = (const int*)d_in[1];
  const int*   dst  = (const int*)d_in[2];
  const float* W_e  = (const float*)d_in[3];
  const float* b_e  = (const float*)d_in[4];
  const float* W_ih = (const float*)d_in[5];
  const float* W_hh = (const float*)d_in[6];
  const float* b_ih = (const float*)d_in[7];
  const float* b_hh = (const float*)d_in[8];
  const float* W_fc = (const float*)d_in[9];
  const float* b_fc = (const float*)d_in[10];

  const int n = in_sizes[0] / D;   // 50000 nodes
  const int E = in_sizes[1];       // 800000 edges
  const int C = out_size / n;      // 10 classes

  // workspace layout: hA | hB | m | a   (each n*D floats; total ~76.8 MB)
  float* hA = (float*)d_ws;
  float* hB = hA + (size_t)n * D;
  float* m  = hB + (size_t)n * D;
  float* a  = m  + (size_t)n * D;

  (void)hipMemcpyAsync(hA, x, (size_t)n * D * sizeof(float),
                       hipMemcpyDeviceToDevice, stream);

  const int threads = 256;
  const int gridNM = (n * D + threads - 1) / threads;
  const long long totalE = (long long)E * D;
  const int gridE = (int)((totalE + threads - 1) / threads);

  const float* hcur = hA;
  float* hnext = hB;
  for (int s = 0; s < NSTEPS; ++s) {
    node_linear_kernel<<<gridNM, threads, 0, stream>>>(hcur, W_e, b_e, m, n, D);
    (void)hipMemsetAsync(a, 0, (size_t)n * D * sizeof(float), stream);
    scatter_add_kernel<<<gridE, threads, 0, stream>>>(m, src, dst, a, E);
    gru_kernel<<<gridNM, threads, 0, stream>>>(a, hcur, hnext,
                                               W_ih, W_hh, b_ih, b_hh, n);
    const float* t = hcur; hcur = hnext; hnext = (float*)t;
  }

  const int gridH = (n * C + threads - 1) / threads;
  head_kernel<<<gridH, threads, 0, stream>>>(hcur, W_fc, b_fc, (float*)d_out, n, C);
}

// Round 4
// 1481.439 us; speedup vs baseline: 7.2393x; 7.2393x over previous
//
#include <hip/hip_runtime.h>

static constexpr int D = 96;      // hidden size
static constexpr int NSTEPS = 4;  // GGNN propagation steps

typedef __attribute__((ext_vector_type(8))) short bf16x8;  // 8 bf16 (4 VGPRs)
typedef __attribute__((ext_vector_type(4))) float f32x4;   // MFMA C/D frag

__device__ __forceinline__ short f32_to_bf16(float x) {
  union { float f; unsigned u; } v; v.f = x;
  unsigned r = v.u + 0x7FFF + ((v.u >> 16) & 1);   // RNE
  return (short)(r >> 16);
}
__device__ __forceinline__ float bf16_to_f32(short h) {
  union { unsigned u; float f; } v; v.u = ((unsigned)(unsigned short)h) << 16;
  return v.f;
}
// split x ~= hi + lo (both bf16); hi RNE, lo = RNE(x - hi)
__device__ __forceinline__ void split_f32(float x, short& hi, short& lo) {
  hi = f32_to_bf16(x);
  lo = f32_to_bf16(x - bf16_to_f32(hi));
}

// A-fragments (hi, lo) for mfma_f32_16x16x32_bf16 from fp32 row-major [*, ld]:
// lane holds row=r0+(lane&15), k = kc*32 + (lane>>4)*8 .. +7
__device__ __forceinline__ void load_a_frag_split(const float* __restrict__ base,
                                                  int ld, int r0, int lane, int kc,
                                                  bf16x8& hi, bf16x8& lo) {
  int row = r0 + (lane & 15);
  int k0 = kc * 32 + ((lane >> 4) << 3);
  const float4* p4 = (const float4*)(base + (size_t)row * ld + k0);
  float4 x0 = p4[0], x1 = p4[1];
  float v[8] = {x0.x, x0.y, x0.z, x0.w, x1.x, x1.y, x1.z, x1.w};
#pragma unroll
  for (int j = 0; j < 8; ++j) {
    short h, l; split_f32(v[j], h, l);
    hi[j] = h; lo[j] = l;
  }
}

// B-fragment: B[k][c] = W[c][k], W row-major bf16 [M,96].
// lane holds col=c0+(lane&15), k = kc*32 + (lane>>4)*8 .. +7 -> 8 consecutive bf16
__device__ __forceinline__ bf16x8 load_b_frag(const short* __restrict__ W,
                                              int c0, int lane, int kc) {
  int c = c0 + (lane & 15);
  int k0 = kc * 32 + ((lane >> 4) << 3);
  return *(const bf16x8*)(W + (size_t)c * D + k0);
}

__global__ void convert_weights_kernel(const float* __restrict__ We,
                                       const float* __restrict__ Wih,
                                       const float* __restrict__ Whh,
                                       short* __restrict__ WeH, short* __restrict__ WeL,
                                       short* __restrict__ WihH, short* __restrict__ WihL,
                                       short* __restrict__ WhhH, short* __restrict__ WhhL) {
  int i = blockIdx.x * blockDim.x + threadIdx.x;
  if (i < D * D) { short h, l; split_f32(We[i], h, l); WeH[i] = h; WeL[i] = l; }
  if (i < 3 * D * D) {
    short h, l;
    split_f32(Wih[i], h, l); WihH[i] = h; WihL[i] = l;
    split_f32(Whh[i], h, l); WhhH[i] = h; WhhL[i] = l;
  }
}

// acc += A*B in split precision: Ahi*Bhi + Ahi*Blo + Alo*Bhi
#define MFMA3(acc, ahi, alo, W_H, W_L, c0, kc)                                        \
  do {                                                                                \
    bf16x8 _bh = load_b_frag(W_H, c0, lane, kc);                                      \
    bf16x8 _bl = load_b_frag(W_L, c0, lane, kc);                                      \
    acc = __builtin_amdgcn_mfma_f32_16x16x32_bf16(ahi, _bh, acc, 0, 0, 0);            \
    acc = __builtin_amdgcn_mfma_f32_16x16x32_bf16(ahi, _bl, acc, 0, 0, 0);            \
    acc = __builtin_amdgcn_mfma_f32_16x16x32_bf16(alo, _bh, acc, 0, 0, 0);            \
  } while (0)

// m = h @ W_e^T + b_e  via split-bf16 MFMA; one wave per 16-row tile
__global__ void gemm_m_kernel(const float* __restrict__ h,
                              const short* __restrict__ WeH,
                              const short* __restrict__ WeL,
                              const float* __restrict__ be,
                              float* __restrict__ m, int n) {
  int wid = (blockIdx.x * blockDim.x + threadIdx.x) >> 6;
  int lane = threadIdx.x & 63;
  int r0 = wid << 4;
  if (r0 >= n) return;
  bf16x8 aHhi[3], aHlo[3];
#pragma unroll
  for (int kc = 0; kc < 3; ++kc)
    load_a_frag_split(h, D, r0, lane, kc, aHhi[kc], aHlo[kc]);
  int col_l = lane & 15;
  int rq = (lane >> 4) << 2;
#pragma unroll
  for (int ct = 0; ct < 6; ++ct) {
    f32x4 acc = {0.f, 0.f, 0.f, 0.f};
#pragma unroll
    for (int kc = 0; kc < 3; ++kc)
      MFMA3(acc, aHhi[kc], aHlo[kc], WeH, WeL, ct * 16, kc);
    int col = ct * 16 + col_l;
    float bias = be[col];
#pragma unroll
    for (int q = 0; q < 4; ++q) {
      int row = r0 + rq + q;
      m[(size_t)row * D + col] = acc[q] + bias;
    }
  }
}

// a[dst[e], d] += m[src[e], d]
__global__ void scatter_add_kernel(const float* __restrict__ m,
                                   const int* __restrict__ src,
                                   const int* __restrict__ dst,
                                   float* __restrict__ a, int E) {
  long long idx = (long long)blockIdx.x * blockDim.x + threadIdx.x;
  long long total = (long long)E * D;
  if (idx >= total) return;
  int e = (int)(idx / D);
  int d = (int)(idx - (long long)e * D);
  int s = src[e];
  int t = dst[e];
  atomicAdd(&a[(size_t)t * D + d], m[(size_t)s * D + d]);
}

// Fused GRU: both gate GEMMs (r/z share accumulators) + elementwise, in-register
__global__ void gru_gemm_kernel(const float* __restrict__ a,
                                const float* __restrict__ h,
                                float* __restrict__ hout,
                                const short* __restrict__ WihH,
                                const short* __restrict__ WihL,
                                const short* __restrict__ WhhH,
                                const short* __restrict__ WhhL,
                                const float* __restrict__ bih,
                                const float* __restrict__ bhh,
                                int n) {
  int wid = (blockIdx.x * blockDim.x + threadIdx.x) >> 6;
  int lane = threadIdx.x & 63;
  int r0 = wid << 4;
  if (r0 >= n) return;
  bf16x8 aAhi[3], aAlo[3], aHhi[3], aHlo[3];
#pragma unroll
  for (int kc = 0; kc < 3; ++kc) {
    load_a_frag_split(a, D, r0, lane, kc, aAhi[kc], aAlo[kc]);
    load_a_frag_split(h, D, r0, lane, kc, aHhi[kc], aHlo[kc]);
  }
  f32x4 accR[6], accZ[6], accXN[6], accHN[6];
#pragma unroll
  for (int t = 0; t < 6; ++t) {
    accR[t] = (f32x4){0.f, 0.f, 0.f, 0.f};
    accZ[t] = (f32x4){0.f, 0.f, 0.f, 0.f};
    accXN[t] = (f32x4){0.f, 0.f, 0.f, 0.f};
    accHN[t] = (f32x4){0.f, 0.f, 0.f, 0.f};
  }
#pragma unroll
  for (int ct = 0; ct < 6; ++ct) {
#pragma unroll
    for (int kc = 0; kc < 3; ++kc) {
      MFMA3(accR[ct], aAhi[kc], aAlo[kc], WihH, WihL, ct * 16, kc);
      MFMA3(accR[ct], aHhi[kc], aHlo[kc], WhhH, WhhL, ct * 16, kc);
      MFMA3(accZ[ct], aAhi[kc], aAlo[kc], WihH, WihL, 96 + ct * 16, kc);
      MFMA3(accZ[ct], aHhi[kc], aHlo[kc], WhhH, WhhL, 96 + ct * 16, kc);
      MFMA3(accXN[ct], aAhi[kc], aAlo[kc], WihH, WihL, 192 + ct * 16, kc);
      MFMA3(accHN[ct], aHhi[kc], aHlo[kc], WhhH, WhhL, 192 + ct * 16, kc);
    }
  }
  int col_l = lane & 15;
  int rq = (lane >> 4) << 2;
#pragma unroll
  for (int ct = 0; ct < 6; ++ct) {
    int col = ct * 16 + col_l;
    float br = bih[col] + bhh[col];
    float bz = bih[D + col] + bhh[D + col];
    float bxn = bih[2 * D + col];
    float bhn = bhh[2 * D + col];
#pragma unroll
    for (int q = 0; q < 4; ++q) {
      int row = r0 + rq + q;
      float rg = 1.0f / (1.0f + __expf(-(accR[ct][q] + br)));
      float zg = 1.0f / (1.0f + __expf(-(accZ[ct][q] + bz)));
      float ng = tanhf(accXN[ct][q] + bxn + rg * (accHN[ct][q] + bhn));
      float hv = h[(size_t)row * D + col];
      hout[(size_t)row * D + col] = (1.0f - zg) * ng + zg * hv;
    }
  }
}

// logits[i,c] = sum_k elu(h[i,k]) * Wfc[c,k] + bfc[c]
__global__ void head_kernel(const float* __restrict__ h,
                            const float* __restrict__ Wfc,
                            const float* __restrict__ bfc,
                            float* __restrict__ out,
                            int n, int C) {
  int idx = blockIdx.x * blockDim.x + threadIdx.x;
  if (idx >= n * C) return;
  int i = idx / C;
  int c = idx - i * C;
  const float* hr = h + (size_t)i * D;
  const float* wr = Wfc + (size_t)c * D;
  float acc = bfc[c];
#pragma unroll 8
  for (int k = 0; k < D; ++k) {
    float hv = hr[k];
    float e = hv > 0.0f ? hv : (__expf(hv) - 1.0f);
    acc += e * wr[k];
  }
  out[idx] = acc;
}

extern "C" void kernel_launch(void* const* d_in, const int* in_sizes, int n_in,
                              void* d_out, int out_size, void* d_ws, size_t ws_size,
                              hipStream_t stream) {
  const float* x    = (const float*)d_in[0];
  const int*   src  = (const int*)d_in[1];
  const int*   dst  = (const int*)d_in[2];
  const float* W_e  = (const float*)d_in[3];
  const float* b_e  = (const float*)d_in[4];
  const float* W_ih = (const float*)d_in[5];
  const float* W_hh = (const float*)d_in[6];
  const float* b_ih = (const float*)d_in[7];
  const float* b_hh = (const float*)d_in[8];
  const float* W_fc = (const float*)d_in[9];
  const float* b_fc = (const float*)d_in[10];

  const int n = in_sizes[0] / D;   // 50000
  const int E = in_sizes[1];       // 800000
  const int C = out_size / n;      // 10

  // ws layout: hA | hB | m | a (n*D floats each) | split bf16 weights
  float* hA = (float*)d_ws;
  float* hB = hA + (size_t)n * D;
  float* m  = hB + (size_t)n * D;
  float* a  = m  + (size_t)n * D;
  short* WeH  = (short*)(a + (size_t)n * D);
  short* WeL  = WeH + D * D;
  short* WihH = WeL + D * D;
  short* WihL = WihH + 3 * D * D;
  short* WhhH = WihL + 3 * D * D;
  short* WhhL = WhhH + 3 * D * D;

  const int threads = 256;
  convert_weights_kernel<<<(3 * D * D + threads - 1) / threads, threads, 0, stream>>>(
      W_e, W_ih, W_hh, WeH, WeL, WihH, WihL, WhhH, WhhL);

  (void)hipMemcpyAsync(hA, x, (size_t)n * D * sizeof(float),
                       hipMemcpyDeviceToDevice, stream);

  const int nWaves = (n + 15) / 16;                 // 3125
  const int gridG = (nWaves + 3) / 4;               // 4 waves/block
  const long long totalE = (long long)E * D;
  const int gridE = (int)((totalE + threads - 1) / threads);

  const float* hcur = hA;
  float* hnext = hB;
  for (int s = 0; s < NSTEPS; ++s) {
    gemm_m_kernel<<<gridG, threads, 0, stream>>>(hcur, WeH, WeL, b_e, m, n);
    (void)hipMemsetAsync(a, 0, (size_t)n * D * sizeof(float), stream);
    scatter_add_kernel<<<gridE, threads, 0, stream>>>(m, src, dst, a, E);
    gru_gemm_kernel<<<gridG, threads, 0, stream>>>(a, hcur, hnext,
                                                   WihH, WihL, WhhH, WhhL,
                                                   b_ih, b_hh, n);
    const float* t = hcur; hcur = hnext; hnext = (float*)t;
  }

  const int gridH = (n * C + threads - 1) / threads;
  head_kernel<<<gridH, threads, 0, stream>>>(hcur, W_fc, b_fc, (float*)d_out, n, C);
}

// Round 5
// 749.879 us; speedup vs baseline: 14.3017x; 1.9756x over previous
//
#include <hip/hip_runtime.h>

static constexpr int D = 96;       // hidden size
static constexpr int G3 = 3 * D;   // 288 gate rows
static constexpr int NSTEPS = 4;   // GGNN propagation steps

typedef __attribute__((ext_vector_type(8))) short bf16x8;  // 8 bf16 (4 VGPRs)
typedef __attribute__((ext_vector_type(4))) float f32x4;   // MFMA C/D frag

__device__ __forceinline__ short f32_to_bf16(float x) {
  union { float f; unsigned u; } v; v.f = x;
  unsigned r = v.u + 0x7FFF + ((v.u >> 16) & 1);   // RNE
  return (short)(r >> 16);
}
__device__ __forceinline__ float bf16_to_f32(short h) {
  union { unsigned u; float f; } v; v.u = ((unsigned)(unsigned short)h) << 16;
  return v.f;
}
__device__ __forceinline__ void split_f32(float x, short& hi, short& lo) {
  hi = f32_to_bf16(x);
  lo = f32_to_bf16(x - bf16_to_f32(hi));
}

// A-fragments (hi,lo) for mfma_f32_16x16x32_bf16 from fp32 row-major [*, ld]:
// lane holds row=r0+(lane&15), k = kc*32 + (lane>>4)*8 .. +7
__device__ __forceinline__ void load_a_frag_split(const float* __restrict__ base,
                                                  int ld, int r0, int lane, int kc,
                                                  bf16x8& hi, bf16x8& lo) {
  int row = r0 + (lane & 15);
  int k0 = kc * 32 + ((lane >> 4) << 3);
  const float4* p4 = (const float4*)(base + (size_t)row * ld + k0);
  float4 x0 = p4[0], x1 = p4[1];
  float v[8] = {x0.x, x0.y, x0.z, x0.w, x1.x, x1.y, x1.z, x1.w};
#pragma unroll
  for (int j = 0; j < 8; ++j) {
    short h, l; split_f32(v[j], h, l);
    hi[j] = h; lo[j] = l;
  }
}

// B-fragment: B[k][c] = W[c][k], W row-major bf16 [M,96].
__device__ __forceinline__ bf16x8 load_b_frag(const short* __restrict__ W,
                                              int c0, int lane, int kc) {
  int c = c0 + (lane & 15);
  int k0 = kc * 32 + ((lane >> 4) << 3);
  return *(const bf16x8*)(W + (size_t)c * D + k0);
}

// ---------- one-time prep ----------

// W_x[r][k] = sum_c W_ih[r][c] * W_e[c][k]; bxe[r] = sum_c W_ih[r][c] * b_e[c]
__global__ void compute_wx_kernel(const float* __restrict__ Wih,
                                  const float* __restrict__ We,
                                  const float* __restrict__ be,
                                  float* __restrict__ Wx,
                                  float* __restrict__ bxe) {
  int idx = blockIdx.x * blockDim.x + threadIdx.x;
  if (idx < G3 * D) {
    int r = idx / D, k = idx - r * D;
    float acc = 0.f;
    for (int c = 0; c < D; ++c) acc += Wih[r * D + c] * We[c * D + k];
    Wx[idx] = acc;
  } else if (idx < G3 * D + G3) {
    int r = idx - G3 * D;
    float acc = 0.f;
    for (int c = 0; c < D; ++c) acc += Wih[r * D + c] * be[c];
    bxe[r] = acc;
  }
}

__global__ void split_weights_kernel(const float* __restrict__ Wx,
                                     const float* __restrict__ Whh,
                                     short* __restrict__ WxH, short* __restrict__ WxL,
                                     short* __restrict__ WhhH, short* __restrict__ WhhL) {
  int i = blockIdx.x * blockDim.x + threadIdx.x;
  if (i >= G3 * D) return;
  short h, l;
  split_f32(Wx[i], h, l);  WxH[i] = h;  WxL[i] = l;
  split_f32(Whh[i], h, l); WhhH[i] = h; WhhL[i] = l;
}

// ---------- CSR build (per launch; graph static across steps) ----------

__global__ void hist_kernel(const int* __restrict__ dst, int* __restrict__ counts, int E) {
  int e = blockIdx.x * blockDim.x + threadIdx.x;
  if (e < E) atomicAdd(&counts[dst[e]], 1);
}

// single workgroup of 1024 threads: exclusive scan of counts[n] -> row_ptr[n+1]
__global__ void scan_kernel(const int* __restrict__ counts, int* __restrict__ row_ptr, int n) {
  __shared__ int lds[1024];
  int tid = threadIdx.x;
  int per = (n + 1023) >> 10;
  int beg = tid * per;
  int end = beg + per; if (end > n) end = n;
  int sum = 0;
  for (int i = beg; i < end; ++i) sum += counts[i];
  lds[tid] = sum;
  __syncthreads();
  for (int off = 1; off < 1024; off <<= 1) {
    int v = (tid >= off) ? lds[tid - off] : 0;
    __syncthreads();
    lds[tid] += v;
    __syncthreads();
  }
  int run = (tid == 0) ? 0 : lds[tid - 1];
  for (int i = beg; i < end; ++i) { row_ptr[i] = run; run += counts[i]; }
  if (tid == 0) row_ptr[n] = lds[1023];
}

__global__ void fill_kernel(const int* __restrict__ src, const int* __restrict__ dst,
                            const int* __restrict__ row_ptr,
                            int* __restrict__ fillc, int* __restrict__ csr_src, int E) {
  int e = blockIdx.x * blockDim.x + threadIdx.x;
  if (e >= E) return;
  int t = dst[e];
  int pos = row_ptr[t] + atomicAdd(&fillc[t], 1);
  csr_src[pos] = src[e];
}

// ---------- per-step kernels ----------

// s[i,:] = sum over in-edges of h[src,:]   (pull aggregation, wave per node)
__global__ void aggregate_kernel(const float* __restrict__ h,
                                 const int* __restrict__ row_ptr,
                                 const int* __restrict__ csr_src,
                                 float* __restrict__ s, int n) {
  int wid = (blockIdx.x * blockDim.x + threadIdx.x) >> 6;
  int lane = threadIdx.x & 63;
  if (wid >= n) return;
  int beg = row_ptr[wid], end = row_ptr[wid + 1];
  float acc0 = 0.f, acc1 = 0.f;
  int e = beg;
  for (; e + 1 < end; e += 2) {
    int s0 = csr_src[e], s1 = csr_src[e + 1];
    const float* h0 = h + (size_t)s0 * D;
    const float* h1 = h + (size_t)s1 * D;
    float a0 = h0[lane];
    float b0 = h1[lane];
    float a1 = 0.f, b1 = 0.f;
    if (lane < 32) { a1 = h0[64 + lane]; b1 = h1[64 + lane]; }
    acc0 += a0 + b0;
    acc1 += a1 + b1;
  }
  if (e < end) {
    int s0 = csr_src[e];
    const float* h0 = h + (size_t)s0 * D;
    acc0 += h0[lane];
    if (lane < 32) acc1 += h0[64 + lane];
  }
  s[(size_t)wid * D + lane] = acc0;
  if (lane < 32) s[(size_t)wid * D + 64 + lane] = acc1;
}

// acc += A*B split precision: Ahi*Bhi + Ahi*Blo + Alo*Bhi
#define MFMA3(acc, ahi, alo, W_H, W_L, c0, kc)                                        \
  do {                                                                                \
    bf16x8 _bh = load_b_frag(W_H, c0, lane, kc);                                      \
    bf16x8 _bl = load_b_frag(W_L, c0, lane, kc);                                      \
    acc = __builtin_amdgcn_mfma_f32_16x16x32_bf16(ahi, _bh, acc, 0, 0, 0);            \
    acc = __builtin_amdgcn_mfma_f32_16x16x32_bf16(ahi, _bl, acc, 0, 0, 0);            \
    acc = __builtin_amdgcn_mfma_f32_16x16x32_bf16(alo, _bh, acc, 0, 0, 0);            \
  } while (0)

// Fused GRU with folded edge transform:
// gx = s@Wx^T + deg*bxe + b_ih ; gh = h@Whh^T + b_hh ; h' = (1-z)*n + z*h
__global__ void gru_gemm_kernel(const float* __restrict__ s,
                                const float* __restrict__ h,
                                float* __restrict__ hout,
                                const int* __restrict__ row_ptr,
                                const short* __restrict__ WxH,
                                const short* __restrict__ WxL,
                                const short* __restrict__ WhhH,
                                const short* __restrict__ WhhL,
                                const float* __restrict__ bxe,
                                const float* __restrict__ bih,
                                const float* __restrict__ bhh,
                                int n) {
  int wid = (blockIdx.x * blockDim.x + threadIdx.x) >> 6;
  int lane = threadIdx.x & 63;
  int r0 = wid << 4;
  if (r0 >= n) return;
  bf16x8 aShi[3], aSlo[3], aHhi[3], aHlo[3];
#pragma unroll
  for (int kc = 0; kc < 3; ++kc) {
    load_a_frag_split(s, D, r0, lane, kc, aShi[kc], aSlo[kc]);
    load_a_frag_split(h, D, r0, lane, kc, aHhi[kc], aHlo[kc]);
  }
  f32x4 accR[6], accZ[6], accXN[6], accHN[6];
#pragma unroll
  for (int t = 0; t < 6; ++t) {
    accR[t]  = (f32x4){0.f, 0.f, 0.f, 0.f};
    accZ[t]  = (f32x4){0.f, 0.f, 0.f, 0.f};
    accXN[t] = (f32x4){0.f, 0.f, 0.f, 0.f};
    accHN[t] = (f32x4){0.f, 0.f, 0.f, 0.f};
  }
#pragma unroll
  for (int ct = 0; ct < 6; ++ct) {
#pragma unroll
    for (int kc = 0; kc < 3; ++kc) {
      MFMA3(accR[ct],  aShi[kc], aSlo[kc], WxH,  WxL,  ct * 16, kc);
      MFMA3(accR[ct],  aHhi[kc], aHlo[kc], WhhH, WhhL, ct * 16, kc);
      MFMA3(accZ[ct],  aShi[kc], aSlo[kc], WxH,  WxL,  96 + ct * 16, kc);
      MFMA3(accZ[ct],  aHhi[kc], aHlo[kc], WhhH, WhhL, 96 + ct * 16, kc);
      MFMA3(accXN[ct], aShi[kc], aSlo[kc], WxH,  WxL,  192 + ct * 16, kc);
      MFMA3(accHN[ct], aHhi[kc], aHlo[kc], WhhH, WhhL, 192 + ct * 16, kc);
    }
  }
  int col_l = lane & 15;
  int rq = (lane >> 4) << 2;
  float degf[4];
#pragma unroll
  for (int q = 0; q < 4; ++q) {
    int row = r0 + rq + q;
    degf[q] = (float)(row_ptr[row + 1] - row_ptr[row]);
  }
#pragma unroll
  for (int ct = 0; ct < 6; ++ct) {
    int col = ct * 16 + col_l;
    float br  = bih[col] + bhh[col];
    float bz  = bih[D + col] + bhh[D + col];
    float bxn = bih[2 * D + col];
    float bhn = bhh[2 * D + col];
    float xr = bxe[col], xz = bxe[D + col], xn = bxe[2 * D + col];
#pragma unroll
    for (int q = 0; q < 4; ++q) {
      int row = r0 + rq + q;
      float rg = 1.0f / (1.0f + __expf(-(accR[ct][q] + br + degf[q] * xr)));
      float zg = 1.0f / (1.0f + __expf(-(accZ[ct][q] + bz + degf[q] * xz)));
      float ng = tanhf(accXN[ct][q] + bxn + degf[q] * xn + rg * (accHN[ct][q] + bhn));
      float hv = h[(size_t)row * D + col];
      hout[(size_t)row * D + col] = (1.0f - zg) * ng + zg * hv;
    }
  }
}

// logits[i,c] = sum_k elu(h[i,k]) * Wfc[c,k] + bfc[c]
__global__ void head_kernel(const float* __restrict__ h,
                            const float* __restrict__ Wfc,
                            const float* __restrict__ bfc,
                            float* __restrict__ out,
                            int n, int C) {
  int idx = blockIdx.x * blockDim.x + threadIdx.x;
  if (idx >= n * C) return;
  int i = idx / C;
  int c = idx - i * C;
  const float* hr = h + (size_t)i * D;
  const float* wr = Wfc + (size_t)c * D;
  float acc = bfc[c];
#pragma unroll 8
  for (int k = 0; k < D; ++k) {
    float hv = hr[k];
    float e = hv > 0.0f ? hv : (__expf(hv) - 1.0f);
    acc += e * wr[k];
  }
  out[idx] = acc;
}

extern "C" void kernel_launch(void* const* d_in, const int* in_sizes, int n_in,
                              void* d_out, int out_size, void* d_ws, size_t ws_size,
                              hipStream_t stream) {
  const float* x    = (const float*)d_in[0];
  const int*   src  = (const int*)d_in[1];
  const int*   dst  = (const int*)d_in[2];
  const float* W_e  = (const float*)d_in[3];
  const float* b_e  = (const float*)d_in[4];
  const float* W_ih = (const float*)d_in[5];
  const float* W_hh = (const float*)d_in[6];
  const float* b_ih = (const float*)d_in[7];
  const float* b_hh = (const float*)d_in[8];
  const float* W_fc = (const float*)d_in[9];
  const float* b_fc = (const float*)d_in[10];

  const int n = in_sizes[0] / D;   // 50000
  const int E = in_sizes[1];       // 800000
  const int C = out_size / n;      // 10

  // ws layout (16B-aligned chunks first):
  float* hA   = (float*)d_ws;                    // n*D
  float* hB   = hA + (size_t)n * D;              // n*D
  float* s    = hB + (size_t)n * D;              // n*D
  float* Wx   = s + (size_t)n * D;               // G3*D fp32
  short* WxH  = (short*)(Wx + (size_t)G3 * D);   // G3*D bf16 each
  short* WxL  = WxH + (size_t)G3 * D;
  short* WhhH = WxL + (size_t)G3 * D;
  short* WhhL = WhhH + (size_t)G3 * D;
  float* bxe  = (float*)(WhhL + (size_t)G3 * D); // G3 fp32
  int* counts = (int*)(bxe + G3);                // n
  int* fillc  = counts + n;                      // n
  int* row_ptr = fillc + n;                      // n+1
  int* csr_src = row_ptr + (n + 1);              // E

  const int threads = 256;

  // one-time prep (still inside capture; deterministic)
  (void)hipMemsetAsync(counts, 0, (size_t)2 * n * sizeof(int), stream);  // counts+fillc
  hist_kernel<<<(E + threads - 1) / threads, threads, 0, stream>>>(dst, counts, E);
  scan_kernel<<<1, 1024, 0, stream>>>(counts, row_ptr, n);
  fill_kernel<<<(E + threads - 1) / threads, threads, 0, stream>>>(src, dst, row_ptr,
                                                                   fillc, csr_src, E);
  compute_wx_kernel<<<(G3 * D + G3 + threads - 1) / threads, threads, 0, stream>>>(
      W_ih, W_e, b_e, Wx, bxe);
  split_weights_kernel<<<(G3 * D + threads - 1) / threads, threads, 0, stream>>>(
      Wx, W_hh, WxH, WxL, WhhH, WhhL);

  (void)hipMemcpyAsync(hA, x, (size_t)n * D * sizeof(float),
                       hipMemcpyDeviceToDevice, stream);

  const int gridAgg = (n + 3) / 4;                  // 4 waves/block, wave per node
  const int nWaves = (n + 15) / 16;                 // 3125
  const int gridG = (nWaves + 3) / 4;               // 4 waves/block

  const float* hcur = hA;
  float* hnext = hB;
  for (int step = 0; step < NSTEPS; ++step) {
    aggregate_kernel<<<gridAgg, threads, 0, stream>>>(hcur, row_ptr, csr_src, s, n);
    gru_gemm_kernel<<<gridG, threads, 0, stream>>>(s, hcur, hnext, row_ptr,
                                                   WxH, WxL, WhhH, WhhL,
                                                   bxe, b_ih, b_hh, n);
    const float* t = hcur; hcur = hnext; hnext = (float*)t;
  }

  const int gridH = (n * C + threads - 1) / threads;
  head_kernel<<<gridH, threads, 0, stream>>>(hcur, W_fc, b_fc, (float*)d_out, n, C);
}

// Round 6
// 624.512 us; speedup vs baseline: 17.1727x; 1.2007x over previous
//
#include <hip/hip_runtime.h>

static constexpr int D = 96;       // hidden size
static constexpr int G3 = 3 * D;   // 288 gate rows
static constexpr int NSTEPS = 4;   // GGNN propagation steps
static constexpr int NT = 18;      // 288/16 col-tiles per weight matrix

typedef __attribute__((ext_vector_type(8))) short bf16x8;  // 8 bf16 (4 VGPRs)
typedef __attribute__((ext_vector_type(4))) float f32x4;   // MFMA C/D frag

__device__ __forceinline__ short f32_to_bf16(float x) {
  union { float f; unsigned u; } v; v.f = x;
  unsigned r = v.u + 0x7FFF + ((v.u >> 16) & 1);   // RNE
  return (short)(r >> 16);
}
__device__ __forceinline__ float bf16_to_f32(short h) {
  union { unsigned u; float f; } v; v.u = ((unsigned)(unsigned short)h) << 16;
  return v.f;
}
__device__ __forceinline__ void split_f32(float x, short& hi, short& lo) {
  hi = f32_to_bf16(x);
  lo = f32_to_bf16(x - bf16_to_f32(hi));
}

// A-fragments (hi,lo) for mfma_f32_16x16x32_bf16 from fp32 row-major [*,96]:
// lane holds row=r0+(lane&15), k = kc*32 + (lane>>4)*8 .. +7
__device__ __forceinline__ void load_a_frag_split(const float* __restrict__ base,
                                                  int r0, int lane, int kc,
                                                  bf16x8& hi, bf16x8& lo) {
  int row = r0 + (lane & 15);
  int k0 = kc * 32 + ((lane >> 4) << 3);
  const float4* p4 = (const float4*)(base + (size_t)row * D + k0);
  float4 x0 = p4[0], x1 = p4[1];
  float v[8] = {x0.x, x0.y, x0.z, x0.w, x1.x, x1.y, x1.z, x1.w};
#pragma unroll
  for (int j = 0; j < 8; ++j) {
    short h, l; split_f32(v[j], h, l);
    hi[j] = h; lo[j] = l;
  }
}

// Swizzled B-fragment: slot (t,kc) holds 64 lanes' bf16x8 contiguously (1KB)
__device__ __forceinline__ bf16x8 load_b_swz(const short* __restrict__ W,
                                             int t, int kc, int lane) {
  return *(const bf16x8*)(W + (((size_t)t * 3 + kc) * 64 + lane) * 8);
}

// ---------- one-time prep ----------

// W_x[r][k] = sum_c W_ih[r][c] * W_e[c][k]; bxe[r] = sum_c W_ih[r][c] * b_e[c]
__global__ void compute_wx_kernel(const float* __restrict__ Wih,
                                  const float* __restrict__ We,
                                  const float* __restrict__ be,
                                  float* __restrict__ Wx,
                                  float* __restrict__ bxe) {
  int idx = blockIdx.x * blockDim.x + threadIdx.x;
  if (idx < G3 * D) {
    int r = idx / D, k = idx - r * D;
    float acc = 0.f;
    for (int c = 0; c < D; ++c) acc += Wih[r * D + c] * We[c * D + k];
    Wx[idx] = acc;
  } else if (idx < G3 * D + G3) {
    int r = idx - G3 * D;
    float acc = 0.f;
    for (int c = 0; c < D; ++c) acc += Wih[r * D + c] * be[c];
    bxe[r] = acc;
  }
}

// split Wx/Whh into hi/lo bf16, stored in MFMA-fragment (swizzled) order:
// slot (t,kc): lane holds W[c=t*16+(lane&15)][k0=kc*32+(lane>>4)*8 .. +7]
__global__ void swizzle_split_kernel(const float* __restrict__ Wx,
                                     const float* __restrict__ Whh,
                                     short* __restrict__ WxH, short* __restrict__ WxL,
                                     short* __restrict__ WhhH, short* __restrict__ WhhL) {
  int idx = blockIdx.x * blockDim.x + threadIdx.x;
  if (idx >= 2 * NT * 3 * 64) return;
  int mat = idx / (NT * 3 * 64);
  int rem = idx - mat * (NT * 3 * 64);
  int t = rem / (3 * 64);
  int rem2 = rem - t * (3 * 64);
  int kc = rem2 >> 6;
  int lane = rem2 & 63;
  int c = t * 16 + (lane & 15);
  int k0 = kc * 32 + ((lane >> 4) << 3);
  const float* W = mat ? Whh : Wx;
  short* dH = mat ? WhhH : WxH;
  short* dL = mat ? WhhL : WxL;
  bf16x8 hi, lo;
#pragma unroll
  for (int j = 0; j < 8; ++j) {
    short h, l; split_f32(W[(size_t)c * D + k0 + j], h, l);
    hi[j] = h; lo[j] = l;
  }
  size_t slot = ((size_t)t * 3 + kc) * 64 + lane;
  *(bf16x8*)(dH + slot * 8) = hi;
  *(bf16x8*)(dL + slot * 8) = lo;
}

// ---------- CSR build ----------

__global__ void hist_kernel(const int* __restrict__ dst, int* __restrict__ counts, int E) {
  int e = blockIdx.x * blockDim.x + threadIdx.x;
  if (e < E) atomicAdd(&counts[dst[e]], 1);
}

__global__ void scan_kernel(const int* __restrict__ counts, int* __restrict__ row_ptr, int n) {
  __shared__ int lds[1024];
  int tid = threadIdx.x;
  int per = (n + 1023) >> 10;
  int beg = tid * per;
  int end = beg + per; if (end > n) end = n;
  int sum = 0;
  for (int i = beg; i < end; ++i) sum += counts[i];
  lds[tid] = sum;
  __syncthreads();
  for (int off = 1; off < 1024; off <<= 1) {
    int v = (tid >= off) ? lds[tid - off] : 0;
    __syncthreads();
    lds[tid] += v;
    __syncthreads();
  }
  int run = (tid == 0) ? 0 : lds[tid - 1];
  for (int i = beg; i < end; ++i) { row_ptr[i] = run; run += counts[i]; }
  if (tid == 0) row_ptr[n] = lds[1023];
}

__global__ void fill_kernel(const int* __restrict__ src, const int* __restrict__ dst,
                            const int* __restrict__ row_ptr,
                            int* __restrict__ fillc, int* __restrict__ csr_src, int E) {
  int e = blockIdx.x * blockDim.x + threadIdx.x;
  if (e >= E) return;
  int t = dst[e];
  int pos = row_ptr[t] + atomicAdd(&fillc[t], 1);
  csr_src[pos] = src[e];
}

// ---------- per-step kernels ----------

// s[i,:] += h[src,:] over in-edges. Thread per (node, float2 chunk): 48/node.
__global__ void aggregate_kernel(const float* __restrict__ h,
                                 const int* __restrict__ row_ptr,
                                 const int* __restrict__ csr_src,
                                 float* __restrict__ s, int n) {
  int tid = blockIdx.x * blockDim.x + threadIdx.x;
  int i = tid / 48;
  int c2 = tid - i * 48;
  if (i >= n) return;
  int beg = row_ptr[i], end = row_ptr[i + 1];
  const float2* h2 = (const float2*)h;
  float ax = 0.f, ay = 0.f, bx = 0.f, by = 0.f;
  int e = beg;
  for (; e + 1 < end; e += 2) {
    int s0 = csr_src[e], s1 = csr_src[e + 1];
    float2 v0 = h2[(size_t)s0 * 48 + c2];
    float2 v1 = h2[(size_t)s1 * 48 + c2];
    ax += v0.x; ay += v0.y;
    bx += v1.x; by += v1.y;
  }
  if (e < end) {
    float2 v0 = h2[(size_t)csr_src[e] * 48 + c2];
    ax += v0.x; ay += v0.y;
  }
  float2 out; out.x = ax + bx; out.y = ay + by;
  ((float2*)s)[(size_t)i * 48 + c2] = out;
}

// acc += A*B split precision (swizzled B): Ahi*Bhi + Ahi*Blo + Alo*Bhi
#define MFMA3S(acc, ahi, alo, W_H, W_L, t, kc)                                        \
  do {                                                                                \
    bf16x8 _bh = load_b_swz(W_H, t, kc, lane);                                        \
    bf16x8 _bl = load_b_swz(W_L, t, kc, lane);                                        \
    acc = __builtin_amdgcn_mfma_f32_16x16x32_bf16(ahi, _bh, acc, 0, 0, 0);            \
    acc = __builtin_amdgcn_mfma_f32_16x16x32_bf16(ahi, _bl, acc, 0, 0, 0);            \
    acc = __builtin_amdgcn_mfma_f32_16x16x32_bf16(alo, _bh, acc, 0, 0, 0);            \
  } while (0)

// Fused GRU, 4 waves per 16-row tile (one gate-quantity per wave):
// w0: R = s@Wx^T[0:96] + h@Whh^T[0:96]; w1: Z (rows 96:192);
// w2: XN = s@Wx^T[192:288]; w3: HN = h@Whh^T[192:288].
// LDS handoff -> joint elementwise epilogue.
__global__ __launch_bounds__(256) void gru_gemm_kernel(
    const float* __restrict__ s, const float* __restrict__ h,
    float* __restrict__ hout, const int* __restrict__ row_ptr,
    const short* __restrict__ WxH, const short* __restrict__ WxL,
    const short* __restrict__ WhhH, const short* __restrict__ WhhL,
    const float* __restrict__ bxe, const float* __restrict__ bih,
    const float* __restrict__ bhh, int n) {
  __shared__ float lds[4 * 16 * D];
  int r0 = blockIdx.x << 4;
  int w = threadIdx.x >> 6;
  int lane = threadIdx.x & 63;

  f32x4 acc[6];
#pragma unroll
  for (int t = 0; t < 6; ++t) acc[t] = (f32x4){0.f, 0.f, 0.f, 0.f};

  if (w <= 1) {
    bf16x8 sHi[3], sLo[3], hHi[3], hLo[3];
#pragma unroll
    for (int kc = 0; kc < 3; ++kc) {
      load_a_frag_split(s, r0, lane, kc, sHi[kc], sLo[kc]);
      load_a_frag_split(h, r0, lane, kc, hHi[kc], hLo[kc]);
    }
    int t0 = w * 6;
#pragma unroll
    for (int ct = 0; ct < 6; ++ct)
#pragma unroll
      for (int kc = 0; kc < 3; ++kc) {
        MFMA3S(acc[ct], sHi[kc], sLo[kc], WxH, WxL, t0 + ct, kc);
        MFMA3S(acc[ct], hHi[kc], hLo[kc], WhhH, WhhL, t0 + ct, kc);
      }
  } else if (w == 2) {
    bf16x8 sHi[3], sLo[3];
#pragma unroll
    for (int kc = 0; kc < 3; ++kc)
      load_a_frag_split(s, r0, lane, kc, sHi[kc], sLo[kc]);
#pragma unroll
    for (int ct = 0; ct < 6; ++ct)
#pragma unroll
      for (int kc = 0; kc < 3; ++kc)
        MFMA3S(acc[ct], sHi[kc], sLo[kc], WxH, WxL, 12 + ct, kc);
  } else {
    bf16x8 hHi[3], hLo[3];
#pragma unroll
    for (int kc = 0; kc < 3; ++kc)
      load_a_frag_split(h, r0, lane, kc, hHi[kc], hLo[kc]);
#pragma unroll
    for (int ct = 0; ct < 6; ++ct)
#pragma unroll
      for (int kc = 0; kc < 3; ++kc)
        MFMA3S(acc[ct], hHi[kc], hLo[kc], WhhH, WhhL, 12 + ct, kc);
  }

  // C/D layout: col=lane&15, row=(lane>>4)*4+q
  int col_l = lane & 15;
  int rq = (lane >> 4) << 2;
#pragma unroll
  for (int ct = 0; ct < 6; ++ct)
#pragma unroll
    for (int q = 0; q < 4; ++q)
      lds[w * (16 * D) + (rq + q) * D + ct * 16 + col_l] = acc[ct][q];
  __syncthreads();

  // elementwise: 1536 outputs, 256 threads x 6
#pragma unroll
  for (int j = 0; j < 6; ++j) {
    int e = threadIdx.x + j * 256;
    int row = e / D;
    int col = e - row * D;
    int grow = r0 + row;
    float degf = (float)(row_ptr[grow + 1] - row_ptr[grow]);
    float R  = lds[e];
    float Z  = lds[16 * D + e];
    float XN = lds[2 * 16 * D + e];
    float HN = lds[3 * 16 * D + e];
    float rg = 1.0f / (1.0f + __expf(-(R + bih[col] + bhh[col] + degf * bxe[col])));
    float zg = 1.0f / (1.0f + __expf(-(Z + bih[D + col] + bhh[D + col] + degf * bxe[D + col])));
    float ng = tanhf(XN + bih[2 * D + col] + degf * bxe[2 * D + col] + rg * (HN + bhh[2 * D + col]));
    float hv = h[(size_t)grow * D + col];
    hout[(size_t)grow * D + col] = (1.0f - zg) * ng + zg * hv;
  }
}

// logits[i,c] = sum_k elu(h[i,k]) * Wfc[c,k] + bfc[c]
__global__ void head_kernel(const float* __restrict__ h,
                            const float* __restrict__ Wfc,
                            const float* __restrict__ bfc,
                            float* __restrict__ out,
                            int n, int C) {
  int idx = blockIdx.x * blockDim.x + threadIdx.x;
  if (idx >= n * C) return;
  int i = idx / C;
  int c = idx - i * C;
  const float* hr = h + (size_t)i * D;
  const float* wr = Wfc + (size_t)c * D;
  float acc = bfc[c];
#pragma unroll 8
  for (int k = 0; k < D; ++k) {
    float hv = hr[k];
    float e = hv > 0.0f ? hv : (__expf(hv) - 1.0f);
    acc += e * wr[k];
  }
  out[idx] = acc;
}

extern "C" void kernel_launch(void* const* d_in, const int* in_sizes, int n_in,
                              void* d_out, int out_size, void* d_ws, size_t ws_size,
                              hipStream_t stream) {
  const float* x    = (const float*)d_in[0];
  const int*   src  = (const int*)d_in[1];
  const int*   dst  = (const int*)d_in[2];
  const float* W_e  = (const float*)d_in[3];
  const float* b_e  = (const float*)d_in[4];
  const float* W_ih = (const float*)d_in[5];
  const float* W_hh = (const float*)d_in[6];
  const float* b_ih = (const float*)d_in[7];
  const float* b_hh = (const float*)d_in[8];
  const float* W_fc = (const float*)d_in[9];
  const float* b_fc = (const float*)d_in[10];

  const int n = in_sizes[0] / D;   // 50000
  const int E = in_sizes[1];       // 800000
  const int C = out_size / n;      // 10

  // ws layout:
  float* hA   = (float*)d_ws;                    // n*D
  float* hB   = hA + (size_t)n * D;              // n*D
  float* s    = hB + (size_t)n * D;              // n*D
  float* Wx   = s + (size_t)n * D;               // G3*D fp32
  short* WxH  = (short*)(Wx + (size_t)G3 * D);   // G3*D bf16 each (swizzled)
  short* WxL  = WxH + (size_t)G3 * D;
  short* WhhH = WxL + (size_t)G3 * D;
  short* WhhL = WhhH + (size_t)G3 * D;
  float* bxe  = (float*)(WhhL + (size_t)G3 * D); // G3 fp32
  int* counts = (int*)(bxe + G3);                // n
  int* fillc  = counts + n;                      // n
  int* row_ptr = fillc + n;                      // n+1
  int* csr_src = row_ptr + (n + 1);              // E

  const int threads = 256;

  (void)hipMemsetAsync(counts, 0, (size_t)2 * n * sizeof(int), stream);
  hist_kernel<<<(E + threads - 1) / threads, threads, 0, stream>>>(dst, counts, E);
  scan_kernel<<<1, 1024, 0, stream>>>(counts, row_ptr, n);
  fill_kernel<<<(E + threads - 1) / threads, threads, 0, stream>>>(src, dst, row_ptr,
                                                                   fillc, csr_src, E);
  compute_wx_kernel<<<(G3 * D + G3 + threads - 1) / threads, threads, 0, stream>>>(
      W_ih, W_e, b_e, Wx, bxe);
  swizzle_split_kernel<<<(2 * NT * 3 * 64 + threads - 1) / threads, threads, 0, stream>>>(
      Wx, W_hh, WxH, WxL, WhhH, WhhL);

  (void)hipMemcpyAsync(hA, x, (size_t)n * D * sizeof(float),
                       hipMemcpyDeviceToDevice, stream);

  const int gridAgg = ((size_t)n * 48 + threads - 1) / threads;
  const int gridG = (n + 15) / 16;   // one 16-row tile per block (4 waves)

  const float* hcur = hA;
  float* hnext = hB;
  for (int step = 0; step < NSTEPS; ++step) {
    aggregate_kernel<<<gridAgg, threads, 0, stream>>>(hcur, row_ptr, csr_src, s, n);
    gru_gemm_kernel<<<gridG, threads, 0, stream>>>(s, hcur, hnext, row_ptr,
                                                   WxH, WxL, WhhH, WhhL,
                                                   bxe, b_ih, b_hh, n);
    const float* t = hcur; hcur = hnext; hnext = (float*)t;
  }

  const int gridH = (n * C + threads - 1) / threads;
  head_kernel<<<gridH, threads, 0, stream>>>(hcur, W_fc, b_fc, (float*)d_out, n, C);
}

// Round 7
// 521.095 us; speedup vs baseline: 20.5808x; 1.1985x over previous
//
#include <hip/hip_runtime.h>

static constexpr int D = 96;       // hidden size
static constexpr int G3 = 3 * D;   // 288 gate rows
static constexpr int NSTEPS = 4;   // GGNN propagation steps
static constexpr int NT = 18;      // 288/16 col-tiles per weight matrix
static constexpr int SCAN_BLK = 1024;  // elements per scan block

typedef __attribute__((ext_vector_type(8))) short bf16x8;  // 8 bf16 (4 VGPRs)
typedef __attribute__((ext_vector_type(4))) float f32x4;   // MFMA C/D frag

__device__ __forceinline__ short f32_to_bf16(float x) {
  union { float f; unsigned u; } v; v.f = x;
  unsigned r = v.u + 0x7FFF + ((v.u >> 16) & 1);   // RNE
  return (short)(r >> 16);
}
__device__ __forceinline__ float bf16_to_f32(short h) {
  union { unsigned u; float f; } v; v.u = ((unsigned)(unsigned short)h) << 16;
  return v.f;
}
__device__ __forceinline__ void split_f32(float x, short& hi, short& lo) {
  hi = f32_to_bf16(x);
  lo = f32_to_bf16(x - bf16_to_f32(hi));
}

// A-fragments (hi,lo) for mfma_f32_16x16x32_bf16 from fp32 row-major [*,96]:
// lane holds row=r0+(lane&15), k = kc*32 + (lane>>4)*8 .. +7
__device__ __forceinline__ void load_a_frag_split(const float* __restrict__ base,
                                                  int r0, int lane, int kc,
                                                  bf16x8& hi, bf16x8& lo) {
  int row = r0 + (lane & 15);
  int k0 = kc * 32 + ((lane >> 4) << 3);
  const float4* p4 = (const float4*)(base + (size_t)row * D + k0);
  float4 x0 = p4[0], x1 = p4[1];
  float v[8] = {x0.x, x0.y, x0.z, x0.w, x1.x, x1.y, x1.z, x1.w};
#pragma unroll
  for (int j = 0; j < 8; ++j) {
    short h, l; split_f32(v[j], h, l);
    hi[j] = h; lo[j] = l;
  }
}

// Swizzled B-fragment: slot (t,kc) holds 64 lanes' bf16x8 contiguously (1KB)
__device__ __forceinline__ bf16x8 load_b_swz(const short* __restrict__ W,
                                             int t, int kc, int lane) {
  return *(const bf16x8*)(W + (((size_t)t * 3 + kc) * 64 + lane) * 8);
}

// ---------- one-time prep ----------

// W_x[r][k] = sum_c W_ih[r][c] * W_e[c][k]; bxe[r] = sum_c W_ih[r][c] * b_e[c]
__global__ void compute_wx_kernel(const float* __restrict__ Wih,
                                  const float* __restrict__ We,
                                  const float* __restrict__ be,
                                  float* __restrict__ Wx,
                                  float* __restrict__ bxe) {
  int idx = blockIdx.x * blockDim.x + threadIdx.x;
  if (idx < G3 * D) {
    int r = idx / D, k = idx - r * D;
    float acc = 0.f;
    for (int c = 0; c < D; ++c) acc += Wih[r * D + c] * We[c * D + k];
    Wx[idx] = acc;
  } else if (idx < G3 * D + G3) {
    int r = idx - G3 * D;
    float acc = 0.f;
    for (int c = 0; c < D; ++c) acc += Wih[r * D + c] * be[c];
    bxe[r] = acc;
  }
}

// split Wx/Whh into hi/lo bf16, stored in MFMA-fragment (swizzled) order
__global__ void swizzle_split_kernel(const float* __restrict__ Wx,
                                     const float* __restrict__ Whh,
                                     short* __restrict__ WxH, short* __restrict__ WxL,
                                     short* __restrict__ WhhH, short* __restrict__ WhhL) {
  int idx = blockIdx.x * blockDim.x + threadIdx.x;
  if (idx >= 2 * NT * 3 * 64) return;
  int mat = idx / (NT * 3 * 64);
  int rem = idx - mat * (NT * 3 * 64);
  int t = rem / (3 * 64);
  int rem2 = rem - t * (3 * 64);
  int kc = rem2 >> 6;
  int lane = rem2 & 63;
  int c = t * 16 + (lane & 15);
  int k0 = kc * 32 + ((lane >> 4) << 3);
  const float* W = mat ? Whh : Wx;
  short* dH = mat ? WhhH : WxH;
  short* dL = mat ? WhhL : WxL;
  bf16x8 hi, lo;
#pragma unroll
  for (int j = 0; j < 8; ++j) {
    short h, l; split_f32(W[(size_t)c * D + k0 + j], h, l);
    hi[j] = h; lo[j] = l;
  }
  size_t slot = ((size_t)t * 3 + kc) * 64 + lane;
  *(bf16x8*)(dH + slot * 8) = hi;
  *(bf16x8*)(dL + slot * 8) = lo;
}

// ---------- CSR build ----------

__global__ void hist_kernel(const int* __restrict__ dst, int* __restrict__ counts, int E) {
  int e = blockIdx.x * blockDim.x + threadIdx.x;
  if (e < E) atomicAdd(&counts[dst[e]], 1);
}

// phase 1: per-block (1024 elems) sums
__global__ void partial_sum_kernel(const int* __restrict__ counts,
                                   int* __restrict__ blk_sums, int n) {
  __shared__ int red[256];
  int base = blockIdx.x * SCAN_BLK;
  int tid = threadIdx.x;
  int s = 0;
#pragma unroll
  for (int j = 0; j < 4; ++j) {
    int i = base + j * 256 + tid;
    if (i < n) s += counts[i];
  }
  red[tid] = s;
  __syncthreads();
  for (int off = 128; off > 0; off >>= 1) {
    if (tid < off) red[tid] += red[tid + off];
    __syncthreads();
  }
  if (tid == 0) blk_sums[blockIdx.x] = red[0];
}

// phase 2: serial scan of <=64 block sums (tiny)
__global__ void scan_offsets_kernel(const int* __restrict__ blk_sums,
                                    int* __restrict__ blk_off,
                                    int* __restrict__ row_ptr, int nb, int n) {
  __shared__ int lds[64];
  int tid = threadIdx.x;
  if (tid < nb) lds[tid] = blk_sums[tid];
  __syncthreads();
  if (tid == 0) {
    int run = 0;
    for (int i = 0; i < nb; ++i) { blk_off[i] = run; run += lds[i]; }
    row_ptr[n] = run;
  }
}

// phase 3: per-block exclusive scan + global offset
__global__ void block_scan_kernel(const int* __restrict__ counts,
                                  const int* __restrict__ blk_off,
                                  int* __restrict__ row_ptr, int n) {
  __shared__ int red[256];
  int base = blockIdx.x * SCAN_BLK;
  int tid = threadIdx.x;
  int i0 = base + tid * 4;
  int v0 = 0, v1 = 0, v2 = 0, v3 = 0;
  if (i0 + 3 < n) {
    int4 c = *(const int4*)(counts + i0);
    v0 = c.x; v1 = c.y; v2 = c.z; v3 = c.w;
  } else {
    if (i0 < n) v0 = counts[i0];
    if (i0 + 1 < n) v1 = counts[i0 + 1];
    if (i0 + 2 < n) v2 = counts[i0 + 2];
  }
  int tsum = v0 + v1 + v2 + v3;
  red[tid] = tsum;
  __syncthreads();
  for (int off = 1; off < 256; off <<= 1) {
    int t = (tid >= off) ? red[tid - off] : 0;
    __syncthreads();
    red[tid] += t;
    __syncthreads();
  }
  int excl = blk_off[blockIdx.x] + red[tid] - tsum;
  if (i0 < n) row_ptr[i0] = excl;
  if (i0 + 1 < n) row_ptr[i0 + 1] = excl + v0;
  if (i0 + 2 < n) row_ptr[i0 + 2] = excl + v0 + v1;
  if (i0 + 3 < n) row_ptr[i0 + 3] = excl + v0 + v1 + v2;
}

__global__ void fill_kernel(const int* __restrict__ src, const int* __restrict__ dst,
                            const int* __restrict__ row_ptr,
                            int* __restrict__ fillc, int* __restrict__ csr_src, int E) {
  int e = blockIdx.x * blockDim.x + threadIdx.x;
  if (e >= E) return;
  int t = dst[e];
  int pos = row_ptr[t] + atomicAdd(&fillc[t], 1);
  csr_src[pos] = src[e];
}

// ---------- per-step kernels ----------

// s[i,:] += h[src,:] over in-edges. Thread per (node, float2 chunk): 48/node.
__global__ void aggregate_kernel(const float* __restrict__ h,
                                 const int* __restrict__ row_ptr,
                                 const int* __restrict__ csr_src,
                                 float* __restrict__ s, int n) {
  int tid = blockIdx.x * blockDim.x + threadIdx.x;
  int i = tid / 48;
  int c2 = tid - i * 48;
  if (i >= n) return;
  int beg = row_ptr[i], end = row_ptr[i + 1];
  const float2* h2 = (const float2*)h;
  float ax = 0.f, ay = 0.f, bx = 0.f, by = 0.f;
  int e = beg;
  for (; e + 1 < end; e += 2) {
    int s0 = csr_src[e], s1 = csr_src[e + 1];
    float2 v0 = h2[(size_t)s0 * 48 + c2];
    float2 v1 = h2[(size_t)s1 * 48 + c2];
    ax += v0.x; ay += v0.y;
    bx += v1.x; by += v1.y;
  }
  if (e < end) {
    float2 v0 = h2[(size_t)csr_src[e] * 48 + c2];
    ax += v0.x; ay += v0.y;
  }
  float2 out; out.x = ax + bx; out.y = ay + by;
  ((float2*)s)[(size_t)i * 48 + c2] = out;
}

// acc += A*B split precision (swizzled B): Ahi*Bhi + Ahi*Blo + Alo*Bhi
#define MFMA3S(acc, ahi, alo, W_H, W_L, t, kc)                                        \
  do {                                                                                \
    bf16x8 _bh = load_b_swz(W_H, t, kc, lane);                                        \
    bf16x8 _bl = load_b_swz(W_L, t, kc, lane);                                        \
    acc = __builtin_amdgcn_mfma_f32_16x16x32_bf16(ahi, _bh, acc, 0, 0, 0);            \
    acc = __builtin_amdgcn_mfma_f32_16x16x32_bf16(ahi, _bl, acc, 0, 0, 0);            \
    acc = __builtin_amdgcn_mfma_f32_16x16x32_bf16(alo, _bh, acc, 0, 0, 0);            \
  } while (0)

// Fused GRU, 4 waves per 16-row tile, operand-balanced (81 MFMAs each):
//   w0 (s): R_s tiles 0-5 -> plane0, XN tiles 12-14 -> plane4 cols 0-47
//   w1 (s): Z_s tiles 6-11 -> plane2, XN tiles 15-17 -> plane4 cols 48-95
//   w2 (h): R_h tiles 0-5 -> plane1, HN tiles 12-14 -> plane5 cols 0-47
//   w3 (h): Z_h tiles 6-11 -> plane3, HN tiles 15-17 -> plane5 cols 48-95
// Epilogue: R=p0+p1, Z=p2+p3, XN=p4, HN=p5.
__global__ __launch_bounds__(256) void gru_gemm_kernel(
    const float* __restrict__ s, const float* __restrict__ h,
    float* __restrict__ hout, const int* __restrict__ row_ptr,
    const short* __restrict__ WxH, const short* __restrict__ WxL,
    const short* __restrict__ WhhH, const short* __restrict__ WhhL,
    const float* __restrict__ bxe, const float* __restrict__ bih,
    const float* __restrict__ bhh, int n) {
  __shared__ float lds[6 * 16 * D];
  int r0 = blockIdx.x << 4;
  int w = threadIdx.x >> 6;
  int lane = threadIdx.x & 63;

  const int opS = (w < 2) ? 1 : 0;
  const float* A = opS ? s : h;
  const short* WH = opS ? WxH : WhhH;
  const short* WL = opS ? WxL : WhhL;
  const int half = w & 1;
  const int main_t0 = half * 6;                    // tiles for R (0-5) or Z (6-11)
  const int main_plane = half * 2 + (opS ? 0 : 1); // 0=R_s,1=R_h,2=Z_s,3=Z_h
  const int extra_t0 = 12 + half * 3;              // XN/HN tiles
  const int extra_ct0 = half * 3;                  // col-tile offset in plane
  const int extra_plane = opS ? 4 : 5;             // 4=XN, 5=HN

  bf16x8 aHi[3], aLo[3];
#pragma unroll
  for (int kc = 0; kc < 3; ++kc)
    load_a_frag_split(A, r0, lane, kc, aHi[kc], aLo[kc]);

  f32x4 accM[6], accE[3];
#pragma unroll
  for (int t = 0; t < 6; ++t) accM[t] = (f32x4){0.f, 0.f, 0.f, 0.f};
#pragma unroll
  for (int t = 0; t < 3; ++t) accE[t] = (f32x4){0.f, 0.f, 0.f, 0.f};

#pragma unroll
  for (int ct = 0; ct < 6; ++ct)
#pragma unroll
    for (int kc = 0; kc < 3; ++kc)
      MFMA3S(accM[ct], aHi[kc], aLo[kc], WH, WL, main_t0 + ct, kc);
#pragma unroll
  for (int ct = 0; ct < 3; ++ct)
#pragma unroll
    for (int kc = 0; kc < 3; ++kc)
      MFMA3S(accE[ct], aHi[kc], aLo[kc], WH, WL, extra_t0 + ct, kc);

  // C/D layout: col=lane&15, row=(lane>>4)*4+q
  int col_l = lane & 15;
  int rq = (lane >> 4) << 2;
#pragma unroll
  for (int ct = 0; ct < 6; ++ct)
#pragma unroll
    for (int q = 0; q < 4; ++q)
      lds[main_plane * (16 * D) + (rq + q) * D + ct * 16 + col_l] = accM[ct][q];
#pragma unroll
  for (int ct = 0; ct < 3; ++ct)
#pragma unroll
    for (int q = 0; q < 4; ++q)
      lds[extra_plane * (16 * D) + (rq + q) * D + (extra_ct0 + ct) * 16 + col_l] = accE[ct][q];
  __syncthreads();

  // elementwise: 1536 outputs, 256 threads x 6
#pragma unroll
  for (int j = 0; j < 6; ++j) {
    int e = threadIdx.x + j * 256;
    int row = e / D;
    int col = e - row * D;
    int grow = r0 + row;
    float degf = (float)(row_ptr[grow + 1] - row_ptr[grow]);
    float R  = lds[e] + lds[16 * D + e];
    float Z  = lds[2 * 16 * D + e] + lds[3 * 16 * D + e];
    float XN = lds[4 * 16 * D + e];
    float HN = lds[5 * 16 * D + e];
    float rg = 1.0f / (1.0f + __expf(-(R + bih[col] + bhh[col] + degf * bxe[col])));
    float zg = 1.0f / (1.0f + __expf(-(Z + bih[D + col] + bhh[D + col] + degf * bxe[D + col])));
    float ng = tanhf(XN + bih[2 * D + col] + degf * bxe[2 * D + col] + rg * (HN + bhh[2 * D + col]));
    float hv = h[(size_t)grow * D + col];
    hout[(size_t)grow * D + col] = (1.0f - zg) * ng + zg * hv;
  }
}

// logits[i,c] = sum_k elu(h[i,k]) * Wfc[c,k] + bfc[c]
__global__ void head_kernel(const float* __restrict__ h,
                            const float* __restrict__ Wfc,
                            const float* __restrict__ bfc,
                            float* __restrict__ out,
                            int n, int C) {
  int idx = blockIdx.x * blockDim.x + threadIdx.x;
  if (idx >= n * C) return;
  int i = idx / C;
  int c = idx - i * C;
  const float* hr = h + (size_t)i * D;
  const float* wr = Wfc + (size_t)c * D;
  float acc = bfc[c];
#pragma unroll 8
  for (int k = 0; k < D; ++k) {
    float hv = hr[k];
    float e = hv > 0.0f ? hv : (__expf(hv) - 1.0f);
    acc += e * wr[k];
  }
  out[idx] = acc;
}

extern "C" void kernel_launch(void* const* d_in, const int* in_sizes, int n_in,
                              void* d_out, int out_size, void* d_ws, size_t ws_size,
                              hipStream_t stream) {
  const float* x    = (const float*)d_in[0];
  const int*   src  = (const int*)d_in[1];
  const int*   dst  = (const int*)d_in[2];
  const float* W_e  = (const float*)d_in[3];
  const float* b_e  = (const float*)d_in[4];
  const float* W_ih = (const float*)d_in[5];
  const float* W_hh = (const float*)d_in[6];
  const float* b_ih = (const float*)d_in[7];
  const float* b_hh = (const float*)d_in[8];
  const float* W_fc = (const float*)d_in[9];
  const float* b_fc = (const float*)d_in[10];

  const int n = in_sizes[0] / D;   // 50000
  const int E = in_sizes[1];       // 800000
  const int C = out_size / n;      // 10

  // ws layout:
  float* hA   = (float*)d_ws;                    // n*D
  float* hB   = hA + (size_t)n * D;              // n*D
  float* s    = hB + (size_t)n * D;              // n*D
  float* Wx   = s + (size_t)n * D;               // G3*D fp32
  short* WxH  = (short*)(Wx + (size_t)G3 * D);   // G3*D bf16 each (swizzled)
  short* WxL  = WxH + (size_t)G3 * D;
  short* WhhH = WxL + (size_t)G3 * D;
  short* WhhL = WhhH + (size_t)G3 * D;
  float* bxe  = (float*)(WhhL + (size_t)G3 * D); // G3 fp32
  int* counts = (int*)(bxe + G3);                // n
  int* fillc  = counts + n;                      // n
  int* row_ptr = fillc + n;                      // n+1
  int* csr_src = row_ptr + (n + 1);              // E
  int* blk_sums = csr_src + E;                   // <=64
  int* blk_off  = blk_sums + 64;                 // <=64

  const int threads = 256;
  const int nb = (n + SCAN_BLK - 1) / SCAN_BLK;  // 49 scan blocks

  (void)hipMemsetAsync(counts, 0, (size_t)2 * n * sizeof(int), stream);
  hist_kernel<<<(E + threads - 1) / threads, threads, 0, stream>>>(dst, counts, E);
  partial_sum_kernel<<<nb, 256, 0, stream>>>(counts, blk_sums, n);
  scan_offsets_kernel<<<1, 64, 0, stream>>>(blk_sums, blk_off, row_ptr, nb, n);
  block_scan_kernel<<<nb, 256, 0, stream>>>(counts, blk_off, row_ptr, n);
  fill_kernel<<<(E + threads - 1) / threads, threads, 0, stream>>>(src, dst, row_ptr,
                                                                   fillc, csr_src, E);
  compute_wx_kernel<<<(G3 * D + G3 + threads - 1) / threads, threads, 0, stream>>>(
      W_ih, W_e, b_e, Wx, bxe);
  swizzle_split_kernel<<<(2 * NT * 3 * 64 + threads - 1) / threads, threads, 0, stream>>>(
      Wx, W_hh, WxH, WxL, WhhH, WhhL);

  (void)hipMemcpyAsync(hA, x, (size_t)n * D * sizeof(float),
                       hipMemcpyDeviceToDevice, stream);

  const int gridAgg = ((size_t)n * 48 + threads - 1) / threads;
  const int gridG = (n + 15) / 16;   // one 16-row tile per block (4 waves)

  const float* hcur = hA;
  float* hnext = hB;
  for (int step = 0; step < NSTEPS; ++step) {
    aggregate_kernel<<<gridAgg, threads, 0, stream>>>(hcur, row_ptr, csr_src, s, n);
    gru_gemm_kernel<<<gridG, threads, 0, stream>>>(s, hcur, hnext, row_ptr,
                                                   WxH, WxL, WhhH, WhhL,
                                                   bxe, b_ih, b_hh, n);
    const float* t = hcur; hcur = hnext; hnext = (float*)t;
  }

  const int gridH = (n * C + threads - 1) / threads;
  head_kernel<<<gridH, threads, 0, stream>>>(hcur, W_fc, b_fc, (float*)d_out, n, C);
}

// Round 8
// 385.445 us; speedup vs baseline: 27.8237x; 1.3519x over previous
//
#include <hip/hip_runtime.h>

static constexpr int D = 96;       // hidden size
static constexpr int G3 = 3 * D;   // 288 gate rows
static constexpr int NSTEPS = 4;   // GGNN propagation steps
static constexpr int NT = 18;      // 288/16 col-tiles per weight matrix
static constexpr int SCAN_BLK = 1024;  // elements per scan block

typedef __attribute__((ext_vector_type(8))) _Float16 f16x8;  // 8 fp16 (4 VGPRs)
typedef __attribute__((ext_vector_type(4))) _Float16 f16x4;
typedef __attribute__((ext_vector_type(4))) float f32x4;     // MFMA C/D frag

// A-fragment for mfma_f32_16x16x32_f16 from fp16 row-major [*,96]:
// lane holds row=r0+(lane&15), k = kc*32 + (lane>>4)*8 .. +7 -> 16B contiguous
__device__ __forceinline__ f16x8 load_a_frag(const _Float16* __restrict__ base,
                                             int r0, int lane, int kc) {
  int row = r0 + (lane & 15);
  int k0 = kc * 32 + ((lane >> 4) << 3);
  return *(const f16x8*)(base + (size_t)row * D + k0);
}

// Swizzled B-fragment: slot (t,kc) holds 64 lanes' f16x8 contiguously (1KB)
__device__ __forceinline__ f16x8 load_b_swz(const _Float16* __restrict__ W,
                                            int t, int kc, int lane) {
  return *(const f16x8*)(W + (((size_t)t * 3 + kc) * 64 + lane) * 8);
}

// ---------- one-time prep ----------

// x (fp32) -> h (fp16), 4 elems/thread
__global__ void convert_x_kernel(const float* __restrict__ x,
                                 _Float16* __restrict__ h, int total4) {
  int i = blockIdx.x * blockDim.x + threadIdx.x;
  if (i >= total4) return;
  float4 v = ((const float4*)x)[i];
  f16x4 o;
  o[0] = (_Float16)v.x; o[1] = (_Float16)v.y;
  o[2] = (_Float16)v.z; o[3] = (_Float16)v.w;
  *(f16x4*)(h + (size_t)i * 4) = o;
}

// W_x[r][k] = sum_c W_ih[r][c] * W_e[c][k]; bxe[r] = sum_c W_ih[r][c] * b_e[c]
__global__ void compute_wx_kernel(const float* __restrict__ Wih,
                                  const float* __restrict__ We,
                                  const float* __restrict__ be,
                                  float* __restrict__ Wx,
                                  float* __restrict__ bxe) {
  int idx = blockIdx.x * blockDim.x + threadIdx.x;
  if (idx < G3 * D) {
    int r = idx / D, k = idx - r * D;
    float acc = 0.f;
    for (int c = 0; c < D; ++c) acc += Wih[r * D + c] * We[c * D + k];
    Wx[idx] = acc;
  } else if (idx < G3 * D + G3) {
    int r = idx - G3 * D;
    float acc = 0.f;
    for (int c = 0; c < D; ++c) acc += Wih[r * D + c] * be[c];
    bxe[r] = acc;
  }
}

// convert Wx/Whh to fp16 in MFMA-fragment (swizzled) order:
// slot (t,kc): lane holds W[c=t*16+(lane&15)][k0=kc*32+(lane>>4)*8 .. +7]
__global__ void swizzle_f16_kernel(const float* __restrict__ Wx,
                                   const float* __restrict__ Whh,
                                   _Float16* __restrict__ WxF,
                                   _Float16* __restrict__ WhhF) {
  int idx = blockIdx.x * blockDim.x + threadIdx.x;
  if (idx >= 2 * NT * 3 * 64) return;
  int mat = idx / (NT * 3 * 64);
  int rem = idx - mat * (NT * 3 * 64);
  int t = rem / (3 * 64);
  int rem2 = rem - t * (3 * 64);
  int kc = rem2 >> 6;
  int lane = rem2 & 63;
  int c = t * 16 + (lane & 15);
  int k0 = kc * 32 + ((lane >> 4) << 3);
  const float* W = mat ? Whh : Wx;
  _Float16* dF = mat ? WhhF : WxF;
  f16x8 o;
#pragma unroll
  for (int j = 0; j < 8; ++j) o[j] = (_Float16)W[(size_t)c * D + k0 + j];
  *(f16x8*)(dF + (((size_t)t * 3 + kc) * 64 + lane) * 8) = o;
}

// ---------- CSR build ----------

__global__ void hist_kernel(const int* __restrict__ dst, int* __restrict__ counts, int E) {
  int e = blockIdx.x * blockDim.x + threadIdx.x;
  if (e < E) atomicAdd(&counts[dst[e]], 1);
}

__global__ void partial_sum_kernel(const int* __restrict__ counts,
                                   int* __restrict__ blk_sums, int n) {
  __shared__ int red[256];
  int base = blockIdx.x * SCAN_BLK;
  int tid = threadIdx.x;
  int s = 0;
#pragma unroll
  for (int j = 0; j < 4; ++j) {
    int i = base + j * 256 + tid;
    if (i < n) s += counts[i];
  }
  red[tid] = s;
  __syncthreads();
  for (int off = 128; off > 0; off >>= 1) {
    if (tid < off) red[tid] += red[tid + off];
    __syncthreads();
  }
  if (tid == 0) blk_sums[blockIdx.x] = red[0];
}

__global__ void scan_offsets_kernel(const int* __restrict__ blk_sums,
                                    int* __restrict__ blk_off,
                                    int* __restrict__ row_ptr, int nb, int n) {
  __shared__ int lds[64];
  int tid = threadIdx.x;
  if (tid < nb) lds[tid] = blk_sums[tid];
  __syncthreads();
  if (tid == 0) {
    int run = 0;
    for (int i = 0; i < nb; ++i) { blk_off[i] = run; run += lds[i]; }
    row_ptr[n] = run;
  }
}

__global__ void block_scan_kernel(const int* __restrict__ counts,
                                  const int* __restrict__ blk_off,
                                  int* __restrict__ row_ptr, int n) {
  __shared__ int red[256];
  int base = blockIdx.x * SCAN_BLK;
  int tid = threadIdx.x;
  int i0 = base + tid * 4;
  int v0 = 0, v1 = 0, v2 = 0, v3 = 0;
  if (i0 + 3 < n) {
    int4 c = *(const int4*)(counts + i0);
    v0 = c.x; v1 = c.y; v2 = c.z; v3 = c.w;
  } else {
    if (i0 < n) v0 = counts[i0];
    if (i0 + 1 < n) v1 = counts[i0 + 1];
    if (i0 + 2 < n) v2 = counts[i0 + 2];
  }
  int tsum = v0 + v1 + v2 + v3;
  red[tid] = tsum;
  __syncthreads();
  for (int off = 1; off < 256; off <<= 1) {
    int t = (tid >= off) ? red[tid - off] : 0;
    __syncthreads();
    red[tid] += t;
    __syncthreads();
  }
  int excl = blk_off[blockIdx.x] + red[tid] - tsum;
  if (i0 < n) row_ptr[i0] = excl;
  if (i0 + 1 < n) row_ptr[i0 + 1] = excl + v0;
  if (i0 + 2 < n) row_ptr[i0 + 2] = excl + v0 + v1;
  if (i0 + 3 < n) row_ptr[i0 + 3] = excl + v0 + v1 + v2;
}

__global__ void fill_kernel(const int* __restrict__ src, const int* __restrict__ dst,
                            const int* __restrict__ row_ptr,
                            int* __restrict__ fillc, int* __restrict__ csr_src, int E) {
  int e = blockIdx.x * blockDim.x + threadIdx.x;
  if (e >= E) return;
  int t = dst[e];
  int pos = row_ptr[t] + atomicAdd(&fillc[t], 1);
  csr_src[pos] = src[e];
}

// ---------- per-step kernels ----------

// s[i,:] = sum over in-edges of h[src,:] (fp16 in, fp32 accum, fp16 out)
// thread per (node, 4-elem chunk): 24 threads/node
__global__ void aggregate_kernel(const _Float16* __restrict__ h,
                                 const int* __restrict__ row_ptr,
                                 const int* __restrict__ csr_src,
                                 _Float16* __restrict__ s, int n) {
  int tid = blockIdx.x * blockDim.x + threadIdx.x;
  int i = tid / 24;
  int c4 = tid - i * 24;
  if (i >= n) return;
  int beg = row_ptr[i], end = row_ptr[i + 1];
  float a0 = 0.f, a1 = 0.f, a2 = 0.f, a3 = 0.f;
  float b0 = 0.f, b1 = 0.f, b2 = 0.f, b3 = 0.f;
  int e = beg;
  for (; e + 1 < end; e += 2) {
    int s0 = csr_src[e], s1 = csr_src[e + 1];
    f16x4 v0 = *(const f16x4*)(h + (size_t)s0 * D + c4 * 4);
    f16x4 v1 = *(const f16x4*)(h + (size_t)s1 * D + c4 * 4);
    a0 += (float)v0[0]; a1 += (float)v0[1]; a2 += (float)v0[2]; a3 += (float)v0[3];
    b0 += (float)v1[0]; b1 += (float)v1[1]; b2 += (float)v1[2]; b3 += (float)v1[3];
  }
  if (e < end) {
    f16x4 v0 = *(const f16x4*)(h + (size_t)csr_src[e] * D + c4 * 4);
    a0 += (float)v0[0]; a1 += (float)v0[1]; a2 += (float)v0[2]; a3 += (float)v0[3];
  }
  f16x4 out;
  out[0] = (_Float16)(a0 + b0); out[1] = (_Float16)(a1 + b1);
  out[2] = (_Float16)(a2 + b2); out[3] = (_Float16)(a3 + b3);
  *(f16x4*)(s + (size_t)i * D + c4 * 4) = out;
}

#define MFMAS(acc, a, W, t, kc)                                                       \
  do {                                                                                \
    f16x8 _b = load_b_swz(W, t, kc, lane);                                            \
    acc = __builtin_amdgcn_mfma_f32_16x16x32_f16(a, _b, acc, 0, 0, 0);                \
  } while (0)

// Fused GRU, 4 waves per 16-row tile, operand-balanced (27 MFMAs each):
//   w0 (s): R_s tiles 0-5 -> plane0, XN tiles 12-14 -> plane4 cols 0-47
//   w1 (s): Z_s tiles 6-11 -> plane2, XN tiles 15-17 -> plane4 cols 48-95
//   w2 (h): R_h tiles 0-5 -> plane1, HN tiles 12-14 -> plane5 cols 0-47
//   w3 (h): Z_h tiles 6-11 -> plane3, HN tiles 15-17 -> plane5 cols 48-95
// Epilogue: R=p0+p1, Z=p2+p3, XN=p4, HN=p5.
__global__ __launch_bounds__(256) void gru_gemm_kernel(
    const _Float16* __restrict__ s, const _Float16* __restrict__ h,
    _Float16* __restrict__ hout, const int* __restrict__ row_ptr,
    const _Float16* __restrict__ WxF, const _Float16* __restrict__ WhhF,
    const float* __restrict__ bxe, const float* __restrict__ bih,
    const float* __restrict__ bhh, int n) {
  __shared__ float lds[6 * 16 * D];
  int r0 = blockIdx.x << 4;
  int w = threadIdx.x >> 6;
  int lane = threadIdx.x & 63;

  const int opS = (w < 2) ? 1 : 0;
  const _Float16* A = opS ? s : h;
  const _Float16* WF = opS ? WxF : WhhF;
  const int half = w & 1;
  const int main_t0 = half * 6;
  const int main_plane = half * 2 + (opS ? 0 : 1);
  const int extra_t0 = 12 + half * 3;
  const int extra_ct0 = half * 3;
  const int extra_plane = opS ? 4 : 5;

  f16x8 aF[3];
#pragma unroll
  for (int kc = 0; kc < 3; ++kc) aF[kc] = load_a_frag(A, r0, lane, kc);

  f32x4 accM[6], accE[3];
#pragma unroll
  for (int t = 0; t < 6; ++t) accM[t] = (f32x4){0.f, 0.f, 0.f, 0.f};
#pragma unroll
  for (int t = 0; t < 3; ++t) accE[t] = (f32x4){0.f, 0.f, 0.f, 0.f};

#pragma unroll
  for (int ct = 0; ct < 6; ++ct)
#pragma unroll
    for (int kc = 0; kc < 3; ++kc)
      MFMAS(accM[ct], aF[kc], WF, main_t0 + ct, kc);
#pragma unroll
  for (int ct = 0; ct < 3; ++ct)
#pragma unroll
    for (int kc = 0; kc < 3; ++kc)
      MFMAS(accE[ct], aF[kc], WF, extra_t0 + ct, kc);

  // C/D layout: col=lane&15, row=(lane>>4)*4+q
  int col_l = lane & 15;
  int rq = (lane >> 4) << 2;
#pragma unroll
  for (int ct = 0; ct < 6; ++ct)
#pragma unroll
    for (int q = 0; q < 4; ++q)
      lds[main_plane * (16 * D) + (rq + q) * D + ct * 16 + col_l] = accM[ct][q];
#pragma unroll
  for (int ct = 0; ct < 3; ++ct)
#pragma unroll
    for (int q = 0; q < 4; ++q)
      lds[extra_plane * (16 * D) + (rq + q) * D + (extra_ct0 + ct) * 16 + col_l] = accE[ct][q];
  __syncthreads();

  // elementwise: 1536 outputs, 256 threads x 6
#pragma unroll
  for (int j = 0; j < 6; ++j) {
    int e = threadIdx.x + j * 256;
    int row = e / D;
    int col = e - row * D;
    int grow = r0 + row;
    float degf = (float)(row_ptr[grow + 1] - row_ptr[grow]);
    float R  = lds[e] + lds[16 * D + e];
    float Z  = lds[2 * 16 * D + e] + lds[3 * 16 * D + e];
    float XN = lds[4 * 16 * D + e];
    float HN = lds[5 * 16 * D + e];
    float rg = 1.0f / (1.0f + __expf(-(R + bih[col] + bhh[col] + degf * bxe[col])));
    float zg = 1.0f / (1.0f + __expf(-(Z + bih[D + col] + bhh[D + col] + degf * bxe[D + col])));
    float ng = tanhf(XN + bih[2 * D + col] + degf * bxe[2 * D + col] + rg * (HN + bhh[2 * D + col]));
    float hv = (float)h[(size_t)grow * D + col];
    hout[(size_t)grow * D + col] = (_Float16)((1.0f - zg) * ng + zg * hv);
  }
}

// logits[i,c] = sum_k elu(h[i,k]) * Wfc[c,k] + bfc[c]
__global__ void head_kernel(const _Float16* __restrict__ h,
                            const float* __restrict__ Wfc,
                            const float* __restrict__ bfc,
                            float* __restrict__ out,
                            int n, int C) {
  int idx = blockIdx.x * blockDim.x + threadIdx.x;
  if (idx >= n * C) return;
  int i = idx / C;
  int c = idx - i * C;
  const _Float16* hr = h + (size_t)i * D;
  const float* wr = Wfc + (size_t)c * D;
  float acc = bfc[c];
#pragma unroll 8
  for (int k = 0; k < D; ++k) {
    float hv = (float)hr[k];
    float e = hv > 0.0f ? hv : (__expf(hv) - 1.0f);
    acc += e * wr[k];
  }
  out[idx] = acc;
}

extern "C" void kernel_launch(void* const* d_in, const int* in_sizes, int n_in,
                              void* d_out, int out_size, void* d_ws, size_t ws_size,
                              hipStream_t stream) {
  const float* x    = (const float*)d_in[0];
  const int*   src  = (const int*)d_in[1];
  const int*   dst  = (const int*)d_in[2];
  const float* W_e  = (const float*)d_in[3];
  const float* b_e  = (const float*)d_in[4];
  const float* W_ih = (const float*)d_in[5];
  const float* W_hh = (const float*)d_in[6];
  const float* b_ih = (const float*)d_in[7];
  const float* b_hh = (const float*)d_in[8];
  const float* W_fc = (const float*)d_in[9];
  const float* b_fc = (const float*)d_in[10];

  const int n = in_sizes[0] / D;   // 50000
  const int E = in_sizes[1];       // 800000
  const int C = out_size / n;      // 10

  // ws layout (fp16 state):
  _Float16* hA = (_Float16*)d_ws;                 // n*D fp16
  _Float16* hB = hA + (size_t)n * D;              // n*D fp16
  _Float16* s  = hB + (size_t)n * D;              // n*D fp16
  float* Wx    = (float*)(s + (size_t)n * D);     // G3*D fp32 temp
  _Float16* WxF  = (_Float16*)(Wx + (size_t)G3 * D);  // G3*D fp16 swizzled
  _Float16* WhhF = WxF + (size_t)G3 * D;
  float* bxe   = (float*)(WhhF + (size_t)G3 * D); // G3 fp32
  int* counts  = (int*)(bxe + G3);                // n
  int* fillc   = counts + n;                      // n
  int* row_ptr = fillc + n;                       // n+1
  int* csr_src = row_ptr + (n + 1);               // E
  int* blk_sums = csr_src + E;                    // <=64
  int* blk_off  = blk_sums + 64;                  // <=64

  const int threads = 256;
  const int nb = (n + SCAN_BLK - 1) / SCAN_BLK;

  (void)hipMemsetAsync(counts, 0, (size_t)2 * n * sizeof(int), stream);
  hist_kernel<<<(E + threads - 1) / threads, threads, 0, stream>>>(dst, counts, E);
  partial_sum_kernel<<<nb, 256, 0, stream>>>(counts, blk_sums, n);
  scan_offsets_kernel<<<1, 64, 0, stream>>>(blk_sums, blk_off, row_ptr, nb, n);
  block_scan_kernel<<<nb, 256, 0, stream>>>(counts, blk_off, row_ptr, n);
  fill_kernel<<<(E + threads - 1) / threads, threads, 0, stream>>>(src, dst, row_ptr,
                                                                   fillc, csr_src, E);
  compute_wx_kernel<<<(G3 * D + G3 + threads - 1) / threads, threads, 0, stream>>>(
      W_ih, W_e, b_e, Wx, bxe);
  swizzle_f16_kernel<<<(2 * NT * 3 * 64 + threads - 1) / threads, threads, 0, stream>>>(
      Wx, W_hh, WxF, WhhF);
  convert_x_kernel<<<((n * D / 4) + threads - 1) / threads, threads, 0, stream>>>(
      x, hA, n * D / 4);

  const int gridAgg = ((size_t)n * 24 + threads - 1) / threads;
  const int gridG = (n + 15) / 16;   // one 16-row tile per block (4 waves)

  const _Float16* hcur = hA;
  _Float16* hnext = hB;
  for (int step = 0; step < NSTEPS; ++step) {
    aggregate_kernel<<<gridAgg, threads, 0, stream>>>(hcur, row_ptr, csr_src, s, n);
    gru_gemm_kernel<<<gridG, threads, 0, stream>>>(s, hcur, hnext, row_ptr,
                                                   WxF, WhhF, bxe, b_ih, b_hh, n);
    const _Float16* t = hcur; hcur = hnext; hnext = (_Float16*)t;
  }

  const int gridH = (n * C + threads - 1) / threads;
  head_kernel<<<gridH, threads, 0, stream>>>(hcur, W_fc, b_fc, (float*)d_out, n, C);
}

// Round 9
// 370.813 us; speedup vs baseline: 28.9217x; 1.0395x over previous
//
#include <hip/hip_runtime.h>

static constexpr int D = 96;       // hidden size
static constexpr int G3 = 3 * D;   // 288 gate rows
static constexpr int NSTEPS = 4;   // GGNN propagation steps
static constexpr int NT = 18;      // 288/16 col-tiles per weight matrix
static constexpr int SCAN_BLK = 1024;  // elements per scan block

typedef __attribute__((ext_vector_type(8))) _Float16 f16x8;  // 8 fp16 (4 VGPRs)
typedef __attribute__((ext_vector_type(4))) _Float16 f16x4;
typedef __attribute__((ext_vector_type(4))) float f32x4;     // MFMA C/D frag

// A-fragment for mfma_f32_16x16x32_f16 from fp16 row-major [*,96]:
// lane holds row=r0+(lane&15), k = kc*32 + (lane>>4)*8 .. +7 -> 16B contiguous
__device__ __forceinline__ f16x8 load_a_frag(const _Float16* __restrict__ base,
                                             int r0, int lane, int kc) {
  int row = r0 + (lane & 15);
  int k0 = kc * 32 + ((lane >> 4) << 3);
  return *(const f16x8*)(base + (size_t)row * D + k0);
}

// Swizzled B-fragment: slot (t,kc) holds 64 lanes' f16x8 contiguously (1KB)
__device__ __forceinline__ f16x8 load_b_swz(const _Float16* __restrict__ W,
                                            int t, int kc, int lane) {
  return *(const f16x8*)(W + (((size_t)t * 3 + kc) * 64 + lane) * 8);
}

// ---------- one-time prep ----------

__global__ void convert_x_kernel(const float* __restrict__ x,
                                 _Float16* __restrict__ h, int total4) {
  int i = blockIdx.x * blockDim.x + threadIdx.x;
  if (i >= total4) return;
  float4 v = ((const float4*)x)[i];
  f16x4 o;
  o[0] = (_Float16)v.x; o[1] = (_Float16)v.y;
  o[2] = (_Float16)v.z; o[3] = (_Float16)v.w;
  *(f16x4*)(h + (size_t)i * 4) = o;
}

// W_x[r][k] = sum_c W_ih[r][c] * W_e[c][k]; bxe[r] = sum_c W_ih[r][c] * b_e[c]
__global__ void compute_wx_kernel(const float* __restrict__ Wih,
                                  const float* __restrict__ We,
                                  const float* __restrict__ be,
                                  float* __restrict__ Wx,
                                  float* __restrict__ bxe) {
  int idx = blockIdx.x * blockDim.x + threadIdx.x;
  if (idx < G3 * D) {
    int r = idx / D, k = idx - r * D;
    float acc = 0.f;
    for (int c = 0; c < D; ++c) acc += Wih[r * D + c] * We[c * D + k];
    Wx[idx] = acc;
  } else if (idx < G3 * D + G3) {
    int r = idx - G3 * D;
    float acc = 0.f;
    for (int c = 0; c < D; ++c) acc += Wih[r * D + c] * be[c];
    bxe[r] = acc;
  }
}

// convert Wx/Whh to fp16 in MFMA-fragment (swizzled) order
__global__ void swizzle_f16_kernel(const float* __restrict__ Wx,
                                   const float* __restrict__ Whh,
                                   _Float16* __restrict__ WxF,
                                   _Float16* __restrict__ WhhF) {
  int idx = blockIdx.x * blockDim.x + threadIdx.x;
  if (idx >= 2 * NT * 3 * 64) return;
  int mat = idx / (NT * 3 * 64);
  int rem = idx - mat * (NT * 3 * 64);
  int t = rem / (3 * 64);
  int rem2 = rem - t * (3 * 64);
  int kc = rem2 >> 6;
  int lane = rem2 & 63;
  int c = t * 16 + (lane & 15);
  int k0 = kc * 32 + ((lane >> 4) << 3);
  const float* W = mat ? Whh : Wx;
  _Float16* dF = mat ? WhhF : WxF;
  f16x8 o;
#pragma unroll
  for (int j = 0; j < 8; ++j) o[j] = (_Float16)W[(size_t)c * D + k0 + j];
  *(f16x8*)(dF + (((size_t)t * 3 + kc) * 64 + lane) * 8) = o;
}

// ---------- CSR build ----------

__global__ void hist_kernel(const int* __restrict__ dst, int* __restrict__ counts, int E) {
  int e = blockIdx.x * blockDim.x + threadIdx.x;
  if (e < E) atomicAdd(&counts[dst[e]], 1);
}

__global__ void partial_sum_kernel(const int* __restrict__ counts,
                                   int* __restrict__ blk_sums, int n) {
  __shared__ int red[256];
  int base = blockIdx.x * SCAN_BLK;
  int tid = threadIdx.x;
  int s = 0;
#pragma unroll
  for (int j = 0; j < 4; ++j) {
    int i = base + j * 256 + tid;
    if (i < n) s += counts[i];
  }
  red[tid] = s;
  __syncthreads();
  for (int off = 128; off > 0; off >>= 1) {
    if (tid < off) red[tid] += red[tid + off];
    __syncthreads();
  }
  if (tid == 0) blk_sums[blockIdx.x] = red[0];
}

__global__ void scan_offsets_kernel(const int* __restrict__ blk_sums,
                                    int* __restrict__ blk_off,
                                    int* __restrict__ row_ptr, int nb, int n) {
  __shared__ int lds[64];
  int tid = threadIdx.x;
  if (tid < nb) lds[tid] = blk_sums[tid];
  __syncthreads();
  if (tid == 0) {
    int run = 0;
    for (int i = 0; i < nb; ++i) { blk_off[i] = run; run += lds[i]; }
    row_ptr[n] = run;
  }
}

__global__ void block_scan_kernel(const int* __restrict__ counts,
                                  const int* __restrict__ blk_off,
                                  int* __restrict__ row_ptr, int n) {
  __shared__ int red[256];
  int base = blockIdx.x * SCAN_BLK;
  int tid = threadIdx.x;
  int i0 = base + tid * 4;
  int v0 = 0, v1 = 0, v2 = 0, v3 = 0;
  if (i0 + 3 < n) {
    int4 c = *(const int4*)(counts + i0);
    v0 = c.x; v1 = c.y; v2 = c.z; v3 = c.w;
  } else {
    if (i0 < n) v0 = counts[i0];
    if (i0 + 1 < n) v1 = counts[i0 + 1];
    if (i0 + 2 < n) v2 = counts[i0 + 2];
  }
  int tsum = v0 + v1 + v2 + v3;
  red[tid] = tsum;
  __syncthreads();
  for (int off = 1; off < 256; off <<= 1) {
    int t = (tid >= off) ? red[tid - off] : 0;
    __syncthreads();
    red[tid] += t;
    __syncthreads();
  }
  int excl = blk_off[blockIdx.x] + red[tid] - tsum;
  if (i0 < n) row_ptr[i0] = excl;
  if (i0 + 1 < n) row_ptr[i0 + 1] = excl + v0;
  if (i0 + 2 < n) row_ptr[i0 + 2] = excl + v0 + v1;
  if (i0 + 3 < n) row_ptr[i0 + 3] = excl + v0 + v1 + v2;
}

__global__ void fill_kernel(const int* __restrict__ src, const int* __restrict__ dst,
                            const int* __restrict__ row_ptr,
                            int* __restrict__ fillc, int* __restrict__ csr_src, int E) {
  int e = blockIdx.x * blockDim.x + threadIdx.x;
  if (e >= E) return;
  int t = dst[e];
  int pos = row_ptr[t] + atomicAdd(&fillc[t], 1);
  __builtin_nontemporal_store(src[e], &csr_src[pos]);
}

// ---------- per-step kernels ----------

// s[i,:] = sum over in-edges of h[src,:] (fp16 in, fp32 accum, fp16 out)
// thread per (node, 8-elem chunk): 12 threads/node, 4-edge unroll
__global__ void aggregate_kernel(const _Float16* __restrict__ h,
                                 const int* __restrict__ row_ptr,
                                 const int* __restrict__ csr_src,
                                 _Float16* __restrict__ s, int n) {
  int tid = blockIdx.x * blockDim.x + threadIdx.x;
  int i = tid / 12;
  int c8 = tid - i * 12;
  if (i >= n) return;
  int beg = row_ptr[i], end = row_ptr[i + 1];
  float acc[8] = {0.f, 0.f, 0.f, 0.f, 0.f, 0.f, 0.f, 0.f};
  int e = beg;
  for (; e + 3 < end; e += 4) {
    int s0 = csr_src[e], s1 = csr_src[e + 1], s2 = csr_src[e + 2], s3 = csr_src[e + 3];
    f16x8 v0 = *(const f16x8*)(h + (size_t)s0 * D + c8 * 8);
    f16x8 v1 = *(const f16x8*)(h + (size_t)s1 * D + c8 * 8);
    f16x8 v2 = *(const f16x8*)(h + (size_t)s2 * D + c8 * 8);
    f16x8 v3 = *(const f16x8*)(h + (size_t)s3 * D + c8 * 8);
#pragma unroll
    for (int j = 0; j < 8; ++j)
      acc[j] += (float)v0[j] + (float)v1[j] + ((float)v2[j] + (float)v3[j]);
  }
  for (; e < end; ++e) {
    f16x8 v = *(const f16x8*)(h + (size_t)csr_src[e] * D + c8 * 8);
#pragma unroll
    for (int j = 0; j < 8; ++j) acc[j] += (float)v[j];
  }
  f16x8 out;
#pragma unroll
  for (int j = 0; j < 8; ++j) out[j] = (_Float16)acc[j];
  *(f16x8*)(s + (size_t)i * D + c8 * 8) = out;
}

// stores one tile's accs into the 6 LDS planes
__device__ __forceinline__ void store_planes(float* lds, const f32x4* accM,
                                             const f32x4* accE, int main_plane,
                                             int extra_plane, int extra_ct0, int lane) {
  int col_l = lane & 15;
  int rq = (lane >> 4) << 2;
#pragma unroll
  for (int ct = 0; ct < 6; ++ct)
#pragma unroll
    for (int q = 0; q < 4; ++q)
      lds[main_plane * (16 * D) + (rq + q) * D + ct * 16 + col_l] = accM[ct][q];
#pragma unroll
  for (int ct = 0; ct < 3; ++ct)
#pragma unroll
    for (int q = 0; q < 4; ++q)
      lds[extra_plane * (16 * D) + (rq + q) * D + (extra_ct0 + ct) * 16 + col_l] = accE[ct][q];
}

// elementwise GRU epilogue over one 16-row tile staged in LDS planes
__device__ __forceinline__ void gru_epilogue(const float* lds,
                                             const _Float16* __restrict__ h,
                                             _Float16* __restrict__ hout,
                                             const int* __restrict__ row_ptr,
                                             const float* __restrict__ bxe,
                                             const float* __restrict__ bih,
                                             const float* __restrict__ bhh,
                                             int base_row, int tid) {
#pragma unroll
  for (int j = 0; j < 6; ++j) {
    int e = tid + j * 256;
    int row = e / D;
    int col = e - row * D;
    int grow = base_row + row;
    float degf = (float)(row_ptr[grow + 1] - row_ptr[grow]);
    float R  = lds[e] + lds[16 * D + e];
    float Z  = lds[2 * 16 * D + e] + lds[3 * 16 * D + e];
    float XN = lds[4 * 16 * D + e];
    float HN = lds[5 * 16 * D + e];
    float rg = 1.0f / (1.0f + __expf(-(R + bih[col] + bhh[col] + degf * bxe[col])));
    float zg = 1.0f / (1.0f + __expf(-(Z + bih[D + col] + bhh[D + col] + degf * bxe[D + col])));
    float ng = tanhf(XN + bih[2 * D + col] + degf * bxe[2 * D + col] + rg * (HN + bhh[2 * D + col]));
    float hv = (float)h[(size_t)grow * D + col];
    hout[(size_t)grow * D + col] = (_Float16)((1.0f - zg) * ng + zg * hv);
  }
}

// Fused GRU, 4 waves per block, TWO 16-row tiles per block (B-frag reuse x2).
// Wave roles (operand-balanced):
//   w0 (s): R_s tiles 0-5 -> plane0, XN tiles 12-14 -> plane4 cols 0-47
//   w1 (s): Z_s tiles 6-11 -> plane2, XN tiles 15-17 -> plane4 cols 48-95
//   w2 (h): R_h tiles 0-5 -> plane1, HN tiles 12-14 -> plane5 cols 0-47
//   w3 (h): Z_h tiles 6-11 -> plane3, HN tiles 15-17 -> plane5 cols 48-95
__global__ __launch_bounds__(256) void gru_gemm_kernel(
    const _Float16* __restrict__ s, const _Float16* __restrict__ h,
    _Float16* __restrict__ hout, const int* __restrict__ row_ptr,
    const _Float16* __restrict__ WxF, const _Float16* __restrict__ WhhF,
    const float* __restrict__ bxe, const float* __restrict__ bih,
    const float* __restrict__ bhh, int n) {
  __shared__ float lds[6 * 16 * D];
  int r0 = blockIdx.x << 5;   // 32 rows per block
  int w = threadIdx.x >> 6;
  int lane = threadIdx.x & 63;

  const int opS = (w < 2) ? 1 : 0;
  const _Float16* A = opS ? s : h;
  const _Float16* WF = opS ? WxF : WhhF;
  const int half = w & 1;
  const int main_t0 = half * 6;
  const int main_plane = half * 2 + (opS ? 0 : 1);
  const int extra_t0 = 12 + half * 3;
  const int extra_ct0 = half * 3;
  const int extra_plane = opS ? 4 : 5;

  f16x8 a0[3], a1[3];
#pragma unroll
  for (int kc = 0; kc < 3; ++kc) {
    a0[kc] = load_a_frag(A, r0, lane, kc);
    a1[kc] = load_a_frag(A, r0 + 16, lane, kc);
  }

  f32x4 accM0[6], accM1[6], accE0[3], accE1[3];
#pragma unroll
  for (int t = 0; t < 6; ++t) {
    accM0[t] = (f32x4){0.f, 0.f, 0.f, 0.f};
    accM1[t] = (f32x4){0.f, 0.f, 0.f, 0.f};
  }
#pragma unroll
  for (int t = 0; t < 3; ++t) {
    accE0[t] = (f32x4){0.f, 0.f, 0.f, 0.f};
    accE1[t] = (f32x4){0.f, 0.f, 0.f, 0.f};
  }

#pragma unroll
  for (int ct = 0; ct < 6; ++ct)
#pragma unroll
    for (int kc = 0; kc < 3; ++kc) {
      f16x8 b = load_b_swz(WF, main_t0 + ct, kc, lane);
      accM0[ct] = __builtin_amdgcn_mfma_f32_16x16x32_f16(a0[kc], b, accM0[ct], 0, 0, 0);
      accM1[ct] = __builtin_amdgcn_mfma_f32_16x16x32_f16(a1[kc], b, accM1[ct], 0, 0, 0);
    }
#pragma unroll
  for (int ct = 0; ct < 3; ++ct)
#pragma unroll
    for (int kc = 0; kc < 3; ++kc) {
      f16x8 b = load_b_swz(WF, extra_t0 + ct, kc, lane);
      accE0[ct] = __builtin_amdgcn_mfma_f32_16x16x32_f16(a0[kc], b, accE0[ct], 0, 0, 0);
      accE1[ct] = __builtin_amdgcn_mfma_f32_16x16x32_f16(a1[kc], b, accE1[ct], 0, 0, 0);
    }

  // tile 0 epilogue
  store_planes(lds, accM0, accE0, main_plane, extra_plane, extra_ct0, lane);
  __syncthreads();
  gru_epilogue(lds, h, hout, row_ptr, bxe, bih, bhh, r0, threadIdx.x);
  __syncthreads();
  // tile 1 epilogue (last block may have no valid tile 1: n=50000, uniform skip)
  if (r0 + 16 < n) {
    store_planes(lds, accM1, accE1, main_plane, extra_plane, extra_ct0, lane);
    __syncthreads();
    gru_epilogue(lds, h, hout, row_ptr, bxe, bih, bhh, r0 + 16, threadIdx.x);
  }
}

// logits[i,c] = sum_k elu(h[i,k]) * Wfc[c,k] + bfc[c]
__global__ void head_kernel(const _Float16* __restrict__ h,
                            const float* __restrict__ Wfc,
                            const float* __restrict__ bfc,
                            float* __restrict__ out,
                            int n, int C) {
  int idx = blockIdx.x * blockDim.x + threadIdx.x;
  if (idx >= n * C) return;
  int i = idx / C;
  int c = idx - i * C;
  const _Float16* hr = h + (size_t)i * D;
  const float* wr = Wfc + (size_t)c * D;
  float acc = bfc[c];
#pragma unroll 8
  for (int k = 0; k < D; ++k) {
    float hv = (float)hr[k];
    float e = hv > 0.0f ? hv : (__expf(hv) - 1.0f);
    acc += e * wr[k];
  }
  out[idx] = acc;
}

extern "C" void kernel_launch(void* const* d_in, const int* in_sizes, int n_in,
                              void* d_out, int out_size, void* d_ws, size_t ws_size,
                              hipStream_t stream) {
  const float* x    = (const float*)d_in[0];
  const int*   src  = (const int*)d_in[1];
  const int*   dst  = (const int*)d_in[2];
  const float* W_e  = (const float*)d_in[3];
  const float* b_e  = (const float*)d_in[4];
  const float* W_ih = (const float*)d_in[5];
  const float* W_hh = (const float*)d_in[6];
  const float* b_ih = (const float*)d_in[7];
  const float* b_hh = (const float*)d_in[8];
  const float* W_fc = (const float*)d_in[9];
  const float* b_fc = (const float*)d_in[10];

  const int n = in_sizes[0] / D;   // 50000
  const int E = in_sizes[1];       // 800000
  const int C = out_size / n;      // 10

  // ws layout (fp16 state):
  _Float16* hA = (_Float16*)d_ws;                 // n*D fp16
  _Float16* hB = hA + (size_t)n * D;              // n*D fp16
  _Float16* s  = hB + (size_t)n * D;              // n*D fp16
  float* Wx    = (float*)(s + (size_t)n * D);     // G3*D fp32 temp
  _Float16* WxF  = (_Float16*)(Wx + (size_t)G3 * D);  // G3*D fp16 swizzled
  _Float16* WhhF = WxF + (size_t)G3 * D;
  float* bxe   = (float*)(WhhF + (size_t)G3 * D); // G3 fp32
  int* counts  = (int*)(bxe + G3);                // n
  int* fillc   = counts + n;                      // n
  int* row_ptr = fillc + n;                       // n+1
  int* csr_src = row_ptr + (n + 1);               // E
  int* blk_sums = csr_src + E;                    // <=64
  int* blk_off  = blk_sums + 64;                  // <=64

  const int threads = 256;
  const int nb = (n + SCAN_BLK - 1) / SCAN_BLK;

  (void)hipMemsetAsync(counts, 0, (size_t)2 * n * sizeof(int), stream);
  hist_kernel<<<(E + threads - 1) / threads, threads, 0, stream>>>(dst, counts, E);
  partial_sum_kernel<<<nb, 256, 0, stream>>>(counts, blk_sums, n);
  scan_offsets_kernel<<<1, 64, 0, stream>>>(blk_sums, blk_off, row_ptr, nb, n);
  block_scan_kernel<<<nb, 256, 0, stream>>>(counts, blk_off, row_ptr, n);
  fill_kernel<<<(E + threads - 1) / threads, threads, 0, stream>>>(src, dst, row_ptr,
                                                                   fillc, csr_src, E);
  compute_wx_kernel<<<(G3 * D + G3 + threads - 1) / threads, threads, 0, stream>>>(
      W_ih, W_e, b_e, Wx, bxe);
  swizzle_f16_kernel<<<(2 * NT * 3 * 64 + threads - 1) / threads, threads, 0, stream>>>(
      Wx, W_hh, WxF, WhhF);
  convert_x_kernel<<<((n * D / 4) + threads - 1) / threads, threads, 0, stream>>>(
      x, hA, n * D / 4);

  const int gridAgg = (int)(((size_t)n * 12 + threads - 1) / threads);
  const int gridG = (n + 31) / 32;   // two 16-row tiles per block (4 waves)

  const _Float16* hcur = hA;
  _Float16* hnext = hB;
  for (int step = 0; step < NSTEPS; ++step) {
    aggregate_kernel<<<gridAgg, threads, 0, stream>>>(hcur, row_ptr, csr_src, s, n);
    gru_gemm_kernel<<<gridG, threads, 0, stream>>>(s, hcur, hnext, row_ptr,
                                                   WxF, WhhF, bxe, b_ih, b_hh, n);
    const _Float16* t = hcur; hcur = hnext; hnext = (_Float16*)t;
  }

  const int gridH = (n * C + threads - 1) / threads;
  head_kernel<<<gridH, threads, 0, stream>>>(hcur, W_fc, b_fc, (float*)d_out, n, C);
}

// Round 10
// 362.647 us; speedup vs baseline: 29.5729x; 1.0225x over previous
//
#include <hip/hip_runtime.h>

static constexpr int D = 96;       // hidden size
static constexpr int G3 = 3 * D;   // 288 gate rows
static constexpr int NSTEPS = 4;   // GGNN propagation steps
static constexpr int NT = 18;      // 288/16 col-tiles per weight matrix
static constexpr int SCAN_BLK = 1024;  // elements per scan block
static constexpr int SLP = 104;    // s-tile LDS row pad (fp16): 208B stride -> 2-way bank alias

typedef __attribute__((ext_vector_type(8))) _Float16 f16x8;  // 8 fp16 (4 VGPRs)
typedef __attribute__((ext_vector_type(4))) _Float16 f16x4;
typedef __attribute__((ext_vector_type(4))) float f32x4;     // MFMA C/D frag

// A-fragment for mfma_f32_16x16x32_f16 from fp16 row-major [*,96]:
// lane holds row=r0+(lane&15), k = kc*32 + (lane>>4)*8 .. +7 -> 16B contiguous
__device__ __forceinline__ f16x8 load_a_frag(const _Float16* __restrict__ base,
                                             int r0, int lane, int kc) {
  int row = r0 + (lane & 15);
  int k0 = kc * 32 + ((lane >> 4) << 3);
  return *(const f16x8*)(base + (size_t)row * D + k0);
}

// Swizzled B-fragment: slot (t,kc) holds 64 lanes' f16x8 contiguously (1KB)
__device__ __forceinline__ f16x8 load_b_swz(const _Float16* __restrict__ W,
                                            int t, int kc, int lane) {
  return *(const f16x8*)(W + (((size_t)t * 3 + kc) * 64 + lane) * 8);
}

// ---------- one-time prep ----------

__global__ void convert_x_kernel(const float* __restrict__ x,
                                 _Float16* __restrict__ h, int total4) {
  int i = blockIdx.x * blockDim.x + threadIdx.x;
  if (i >= total4) return;
  float4 v = ((const float4*)x)[i];
  f16x4 o;
  o[0] = (_Float16)v.x; o[1] = (_Float16)v.y;
  o[2] = (_Float16)v.z; o[3] = (_Float16)v.w;
  *(f16x4*)(h + (size_t)i * 4) = o;
}

// W_x[r][k] = sum_c W_ih[r][c] * W_e[c][k]; bxe[r] = sum_c W_ih[r][c] * b_e[c]
__global__ void compute_wx_kernel(const float* __restrict__ Wih,
                                  const float* __restrict__ We,
                                  const float* __restrict__ be,
                                  float* __restrict__ Wx,
                                  float* __restrict__ bxe) {
  int idx = blockIdx.x * blockDim.x + threadIdx.x;
  if (idx < G3 * D) {
    int r = idx / D, k = idx - r * D;
    float acc = 0.f;
    for (int c = 0; c < D; ++c) acc += Wih[r * D + c] * We[c * D + k];
    Wx[idx] = acc;
  } else if (idx < G3 * D + G3) {
    int r = idx - G3 * D;
    float acc = 0.f;
    for (int c = 0; c < D; ++c) acc += Wih[r * D + c] * be[c];
    bxe[r] = acc;
  }
}

// convert Wx/Whh to fp16 in MFMA-fragment (swizzled) order
__global__ void swizzle_f16_kernel(const float* __restrict__ Wx,
                                   const float* __restrict__ Whh,
                                   _Float16* __restrict__ WxF,
                                   _Float16* __restrict__ WhhF) {
  int idx = blockIdx.x * blockDim.x + threadIdx.x;
  if (idx >= 2 * NT * 3 * 64) return;
  int mat = idx / (NT * 3 * 64);
  int rem = idx - mat * (NT * 3 * 64);
  int t = rem / (3 * 64);
  int rem2 = rem - t * (3 * 64);
  int kc = rem2 >> 6;
  int lane = rem2 & 63;
  int c = t * 16 + (lane & 15);
  int k0 = kc * 32 + ((lane >> 4) << 3);
  const float* W = mat ? Whh : Wx;
  _Float16* dF = mat ? WhhF : WxF;
  f16x8 o;
#pragma unroll
  for (int j = 0; j < 8; ++j) o[j] = (_Float16)W[(size_t)c * D + k0 + j];
  *(f16x8*)(dF + (((size_t)t * 3 + kc) * 64 + lane) * 8) = o;
}

// ---------- CSR build ----------

__global__ void hist_kernel(const int* __restrict__ dst, int* __restrict__ counts, int E) {
  int e = blockIdx.x * blockDim.x + threadIdx.x;
  if (e < E) atomicAdd(&counts[dst[e]], 1);
}

__global__ void partial_sum_kernel(const int* __restrict__ counts,
                                   int* __restrict__ blk_sums, int n) {
  __shared__ int red[256];
  int base = blockIdx.x * SCAN_BLK;
  int tid = threadIdx.x;
  int s = 0;
#pragma unroll
  for (int j = 0; j < 4; ++j) {
    int i = base + j * 256 + tid;
    if (i < n) s += counts[i];
  }
  red[tid] = s;
  __syncthreads();
  for (int off = 128; off > 0; off >>= 1) {
    if (tid < off) red[tid] += red[tid + off];
    __syncthreads();
  }
  if (tid == 0) blk_sums[blockIdx.x] = red[0];
}

__global__ void scan_offsets_kernel(const int* __restrict__ blk_sums,
                                    int* __restrict__ blk_off,
                                    int* __restrict__ row_ptr, int nb, int n) {
  __shared__ int lds[64];
  int tid = threadIdx.x;
  if (tid < nb) lds[tid] = blk_sums[tid];
  __syncthreads();
  if (tid == 0) {
    int run = 0;
    for (int i = 0; i < nb; ++i) { blk_off[i] = run; run += lds[i]; }
    row_ptr[n] = run;
  }
}

__global__ void block_scan_kernel(const int* __restrict__ counts,
                                  const int* __restrict__ blk_off,
                                  int* __restrict__ row_ptr, int n) {
  __shared__ int red[256];
  int base = blockIdx.x * SCAN_BLK;
  int tid = threadIdx.x;
  int i0 = base + tid * 4;
  int v0 = 0, v1 = 0, v2 = 0, v3 = 0;
  if (i0 + 3 < n) {
    int4 c = *(const int4*)(counts + i0);
    v0 = c.x; v1 = c.y; v2 = c.z; v3 = c.w;
  } else {
    if (i0 < n) v0 = counts[i0];
    if (i0 + 1 < n) v1 = counts[i0 + 1];
    if (i0 + 2 < n) v2 = counts[i0 + 2];
  }
  int tsum = v0 + v1 + v2 + v3;
  red[tid] = tsum;
  __syncthreads();
  for (int off = 1; off < 256; off <<= 1) {
    int t = (tid >= off) ? red[tid - off] : 0;
    __syncthreads();
    red[tid] += t;
    __syncthreads();
  }
  int excl = blk_off[blockIdx.x] + red[tid] - tsum;
  if (i0 < n) row_ptr[i0] = excl;
  if (i0 + 1 < n) row_ptr[i0 + 1] = excl + v0;
  if (i0 + 2 < n) row_ptr[i0 + 2] = excl + v0 + v1;
  if (i0 + 3 < n) row_ptr[i0 + 3] = excl + v0 + v1 + v2;
}

__global__ void fill_kernel(const int* __restrict__ src, const int* __restrict__ dst,
                            const int* __restrict__ row_ptr,
                            int* __restrict__ fillc, int* __restrict__ csr_src, int E) {
  int e = blockIdx.x * blockDim.x + threadIdx.x;
  if (e >= E) return;
  int t = dst[e];
  int pos = row_ptr[t] + atomicAdd(&fillc[t], 1);
  csr_src[pos] = src[e];   // plain store (nontemporal regressed: R9 WRITE 55->65MB)
}

// ---------- fused per-step kernel ----------

// stores one tile's accs into the 6 LDS planes
__device__ __forceinline__ void store_planes(float* lds, const f32x4* accM,
                                             const f32x4* accE, int main_plane,
                                             int extra_plane, int extra_ct0, int lane) {
  int col_l = lane & 15;
  int rq = (lane >> 4) << 2;
#pragma unroll
  for (int ct = 0; ct < 6; ++ct)
#pragma unroll
    for (int q = 0; q < 4; ++q)
      lds[main_plane * (16 * D) + (rq + q) * D + ct * 16 + col_l] = accM[ct][q];
#pragma unroll
  for (int ct = 0; ct < 3; ++ct)
#pragma unroll
    for (int q = 0; q < 4; ++q)
      lds[extra_plane * (16 * D) + (rq + q) * D + (extra_ct0 + ct) * 16 + col_l] = accE[ct][q];
}

// elementwise GRU epilogue over one 16-row tile staged in LDS planes
__device__ __forceinline__ void gru_epilogue(const float* lds,
                                             const _Float16* __restrict__ h,
                                             _Float16* __restrict__ hout,
                                             const int* __restrict__ row_ptr,
                                             const float* __restrict__ bxe,
                                             const float* __restrict__ bih,
                                             const float* __restrict__ bhh,
                                             int base_row, int tid) {
#pragma unroll
  for (int j = 0; j < 6; ++j) {
    int e = tid + j * 256;
    int row = e / D;
    int col = e - row * D;
    int grow = base_row + row;
    float degf = (float)(row_ptr[grow + 1] - row_ptr[grow]);
    float R  = lds[e] + lds[16 * D + e];
    float Z  = lds[2 * 16 * D + e] + lds[3 * 16 * D + e];
    float XN = lds[4 * 16 * D + e];
    float HN = lds[5 * 16 * D + e];
    float rg = 1.0f / (1.0f + __expf(-(R + bih[col] + bhh[col] + degf * bxe[col])));
    float zg = 1.0f / (1.0f + __expf(-(Z + bih[D + col] + bhh[D + col] + degf * bxe[D + col])));
    float ng = tanhf(XN + bih[2 * D + col] + degf * bxe[2 * D + col] + rg * (HN + bhh[2 * D + col]));
    float hv = (float)h[(size_t)grow * D + col];
    hout[(size_t)grow * D + col] = (_Float16)((1.0f - zg) * ng + zg * hv);
  }
}

// Fused aggregate + GRU. Block = 32 rows, 4 waves.
// Phase 1: all 256 threads gather neighbor sums for the block's 32 rows into
//          LDS s-tile (8 threads/row x 12 fp16, fp32 accum, 2-edge unroll).
// Phase 2: operand-balanced GEMM (w0/w1: s from LDS; w2/w3: h from global),
//          two 16-row tiles per block sharing each B-fragment.
// Phase 3: two-pass LDS epilogue.
__global__ __launch_bounds__(256) void gru_fused_kernel(
    const _Float16* __restrict__ h, _Float16* __restrict__ hout,
    const int* __restrict__ row_ptr, const int* __restrict__ csr_src,
    const _Float16* __restrict__ WxF, const _Float16* __restrict__ WhhF,
    const float* __restrict__ bxe, const float* __restrict__ bih,
    const float* __restrict__ bhh, int n) {
  __shared__ float lds[6 * 16 * D];          // 36.9 KB gate planes
  __shared__ _Float16 sl[32][SLP];           // 6.7 KB aggregated s tile
  int r0 = blockIdx.x << 5;   // 32 rows per block
  int w = threadIdx.x >> 6;
  int lane = threadIdx.x & 63;

  // ---- phase 1: gather ----
  {
    int row = threadIdx.x >> 3;     // 0..31
    int part = threadIdx.x & 7;     // 12 fp16 each
    int grow = r0 + row;
    float acc[12];
#pragma unroll
    for (int j = 0; j < 12; ++j) acc[j] = 0.f;
    if (grow < n) {
      int beg = row_ptr[grow], end = row_ptr[grow + 1];
      int e = beg;
      for (; e + 1 < end; e += 2) {
        const _Float16* p0 = h + (size_t)csr_src[e] * D + part * 12;
        const _Float16* p1 = h + (size_t)csr_src[e + 1] * D + part * 12;
        f16x4 u0 = *(const f16x4*)(p0), u1 = *(const f16x4*)(p0 + 4), u2 = *(const f16x4*)(p0 + 8);
        f16x4 v0 = *(const f16x4*)(p1), v1 = *(const f16x4*)(p1 + 4), v2 = *(const f16x4*)(p1 + 8);
#pragma unroll
        for (int j = 0; j < 4; ++j) {
          acc[j]     += (float)u0[j] + (float)v0[j];
          acc[4 + j] += (float)u1[j] + (float)v1[j];
          acc[8 + j] += (float)u2[j] + (float)v2[j];
        }
      }
      if (e < end) {
        const _Float16* p0 = h + (size_t)csr_src[e] * D + part * 12;
        f16x4 u0 = *(const f16x4*)(p0), u1 = *(const f16x4*)(p0 + 4), u2 = *(const f16x4*)(p0 + 8);
#pragma unroll
        for (int j = 0; j < 4; ++j) {
          acc[j] += (float)u0[j]; acc[4 + j] += (float)u1[j]; acc[8 + j] += (float)u2[j];
        }
      }
    }
    f16x4 o0, o1, o2;
#pragma unroll
    for (int j = 0; j < 4; ++j) {
      o0[j] = (_Float16)acc[j]; o1[j] = (_Float16)acc[4 + j]; o2[j] = (_Float16)acc[8 + j];
    }
    *(f16x4*)&sl[row][part * 12]     = o0;
    *(f16x4*)&sl[row][part * 12 + 4] = o1;
    *(f16x4*)&sl[row][part * 12 + 8] = o2;
  }
  __syncthreads();

  // ---- phase 2: GEMM ----
  const int opS = (w < 2) ? 1 : 0;
  const _Float16* WF = opS ? WxF : WhhF;
  const int half = w & 1;
  const int main_t0 = half * 6;
  const int main_plane = half * 2 + (opS ? 0 : 1);
  const int extra_t0 = 12 + half * 3;
  const int extra_ct0 = half * 3;
  const int extra_plane = opS ? 4 : 5;

  f16x8 a0[3], a1[3];
  if (opS) {
#pragma unroll
    for (int kc = 0; kc < 3; ++kc) {
      int k0 = kc * 32 + ((lane >> 4) << 3);
      a0[kc] = *(const f16x8*)&sl[lane & 15][k0];
      a1[kc] = *(const f16x8*)&sl[16 + (lane & 15)][k0];
    }
  } else {
#pragma unroll
    for (int kc = 0; kc < 3; ++kc) {
      a0[kc] = load_a_frag(h, r0, lane, kc);
      a1[kc] = load_a_frag(h, r0 + 16, lane, kc);
    }
  }

  f32x4 accM0[6], accM1[6], accE0[3], accE1[3];
#pragma unroll
  for (int t = 0; t < 6; ++t) {
    accM0[t] = (f32x4){0.f, 0.f, 0.f, 0.f};
    accM1[t] = (f32x4){0.f, 0.f, 0.f, 0.f};
  }
#pragma unroll
  for (int t = 0; t < 3; ++t) {
    accE0[t] = (f32x4){0.f, 0.f, 0.f, 0.f};
    accE1[t] = (f32x4){0.f, 0.f, 0.f, 0.f};
  }

#pragma unroll
  for (int ct = 0; ct < 6; ++ct)
#pragma unroll
    for (int kc = 0; kc < 3; ++kc) {
      f16x8 b = load_b_swz(WF, main_t0 + ct, kc, lane);
      accM0[ct] = __builtin_amdgcn_mfma_f32_16x16x32_f16(a0[kc], b, accM0[ct], 0, 0, 0);
      accM1[ct] = __builtin_amdgcn_mfma_f32_16x16x32_f16(a1[kc], b, accM1[ct], 0, 0, 0);
    }
#pragma unroll
  for (int ct = 0; ct < 3; ++ct)
#pragma unroll
    for (int kc = 0; kc < 3; ++kc) {
      f16x8 b = load_b_swz(WF, extra_t0 + ct, kc, lane);
      accE0[ct] = __builtin_amdgcn_mfma_f32_16x16x32_f16(a0[kc], b, accE0[ct], 0, 0, 0);
      accE1[ct] = __builtin_amdgcn_mfma_f32_16x16x32_f16(a1[kc], b, accE1[ct], 0, 0, 0);
    }

  // ---- phase 3: epilogues ----
  __syncthreads();   // sl reads done (a-frags in regs) before reusing LDS? planes separate; barrier orders gather/frag reads vs epilogue writes across waves
  store_planes(lds, accM0, accE0, main_plane, extra_plane, extra_ct0, lane);
  __syncthreads();
  gru_epilogue(lds, h, hout, row_ptr, bxe, bih, bhh, r0, threadIdx.x);
  __syncthreads();
  if (r0 + 16 < n) {
    store_planes(lds, accM1, accE1, main_plane, extra_plane, extra_ct0, lane);
    __syncthreads();
    gru_epilogue(lds, h, hout, row_ptr, bxe, bih, bhh, r0 + 16, threadIdx.x);
  }
}

// logits[i,c] = sum_k elu(h[i,k]) * Wfc[c,k] + bfc[c]
__global__ void head_kernel(const _Float16* __restrict__ h,
                            const float* __restrict__ Wfc,
                            const float* __restrict__ bfc,
                            float* __restrict__ out,
                            int n, int C) {
  int idx = blockIdx.x * blockDim.x + threadIdx.x;
  if (idx >= n * C) return;
  int i = idx / C;
  int c = idx - i * C;
  const _Float16* hr = h + (size_t)i * D;
  const float* wr = Wfc + (size_t)c * D;
  float acc = bfc[c];
#pragma unroll 8
  for (int k = 0; k < D; ++k) {
    float hv = (float)hr[k];
    float e = hv > 0.0f ? hv : (__expf(hv) - 1.0f);
    acc += e * wr[k];
  }
  out[idx] = acc;
}

extern "C" void kernel_launch(void* const* d_in, const int* in_sizes, int n_in,
                              void* d_out, int out_size, void* d_ws, size_t ws_size,
                              hipStream_t stream) {
  const float* x    = (const float*)d_in[0];
  const int*   src  = (const int*)d_in[1];
  const int*   dst  = (const int*)d_in[2];
  const float* W_e  = (const float*)d_in[3];
  const float* b_e  = (const float*)d_in[4];
  const float* W_ih = (const float*)d_in[5];
  const float* W_hh = (const float*)d_in[6];
  const float* b_ih = (const float*)d_in[7];
  const float* b_hh = (const float*)d_in[8];
  const float* W_fc = (const float*)d_in[9];
  const float* b_fc = (const float*)d_in[10];

  const int n = in_sizes[0] / D;   // 50000
  const int E = in_sizes[1];       // 800000
  const int C = out_size / n;      // 10

  // ws layout (fp16 state; s buffer eliminated by fusion):
  _Float16* hA = (_Float16*)d_ws;                 // n*D fp16
  _Float16* hB = hA + (size_t)n * D;              // n*D fp16
  float* Wx    = (float*)(hB + (size_t)n * D);    // G3*D fp32 temp
  _Float16* WxF  = (_Float16*)(Wx + (size_t)G3 * D);  // G3*D fp16 swizzled
  _Float16* WhhF = WxF + (size_t)G3 * D;
  float* bxe   = (float*)(WhhF + (size_t)G3 * D); // G3 fp32
  int* counts  = (int*)(bxe + G3);                // n
  int* fillc   = counts + n;                      // n
  int* row_ptr = fillc + n;                       // n+1
  int* csr_src = row_ptr + (n + 1);               // E
  int* blk_sums = csr_src + E;                    // <=64
  int* blk_off  = blk_sums + 64;                  // <=64

  const int threads = 256;
  const int nb = (n + SCAN_BLK - 1) / SCAN_BLK;

  (void)hipMemsetAsync(counts, 0, (size_t)2 * n * sizeof(int), stream);
  hist_kernel<<<(E + threads - 1) / threads, threads, 0, stream>>>(dst, counts, E);
  partial_sum_kernel<<<nb, 256, 0, stream>>>(counts, blk_sums, n);
  scan_offsets_kernel<<<1, 64, 0, stream>>>(blk_sums, blk_off, row_ptr, nb, n);
  block_scan_kernel<<<nb, 256, 0, stream>>>(counts, blk_off, row_ptr, n);
  fill_kernel<<<(E + threads - 1) / threads, threads, 0, stream>>>(src, dst, row_ptr,
                                                                   fillc, csr_src, E);
  compute_wx_kernel<<<(G3 * D + G3 + threads - 1) / threads, threads, 0, stream>>>(
      W_ih, W_e, b_e, Wx, bxe);
  swizzle_f16_kernel<<<(2 * NT * 3 * 64 + threads - 1) / threads, threads, 0, stream>>>(
      Wx, W_hh, WxF, WhhF);
  convert_x_kernel<<<((n * D / 4) + threads - 1) / threads, threads, 0, stream>>>(
      x, hA, n * D / 4);

  const int gridG = (n + 31) / 32;   // 32 rows per block

  const _Float16* hcur = hA;
  _Float16* hnext = hB;
  for (int step = 0; step < NSTEPS; ++step) {
    gru_fused_kernel<<<gridG, threads, 0, stream>>>(hcur, hnext, row_ptr, csr_src,
                                                    WxF, WhhF, bxe, b_ih, b_hh, n);
    const _Float16* t = hcur; hcur = hnext; hnext = (_Float16*)t;
  }

  const int gridH = (n * C + threads - 1) / threads;
  head_kernel<<<gridH, threads, 0, stream>>>(hcur, W_fc, b_fc, (float*)d_out, n, C);
}

// Round 11
// 356.306 us; speedup vs baseline: 30.0992x; 1.0178x over previous
//
#include <hip/hip_runtime.h>

static constexpr int D = 96;       // hidden size
static constexpr int G3 = 3 * D;   // 288 gate rows
static constexpr int NSTEPS = 4;   // GGNN propagation steps
static constexpr int NT = 18;      // 288/16 col-tiles per weight matrix
static constexpr int SCAN_BLK = 1024;  // elements per scan block
static constexpr int SLP = 104;    // s-tile LDS row pad (fp16): 208B stride, 16B-aligned
static constexpr int PLS = 97;     // plane row stride (dwords): 4*97%32=4 -> group-disjoint banks
static constexpr int PLANE = 16 * PLS;

typedef __attribute__((ext_vector_type(8))) _Float16 f16x8;  // 8 fp16 (4 VGPRs)
typedef __attribute__((ext_vector_type(4))) _Float16 f16x4;
typedef __attribute__((ext_vector_type(4))) float f32x4;     // MFMA C/D frag

// A-fragment for mfma_f32_16x16x32_f16 from fp16 row-major [*,96]:
// lane holds row=r0+(lane&15), k = kc*32 + (lane>>4)*8 .. +7 -> 16B contiguous
__device__ __forceinline__ f16x8 load_a_frag(const _Float16* __restrict__ base,
                                             int r0, int lane, int kc) {
  int row = r0 + (lane & 15);
  int k0 = kc * 32 + ((lane >> 4) << 3);
  return *(const f16x8*)(base + (size_t)row * D + k0);
}

// Swizzled B-fragment: slot (t,kc) holds 64 lanes' f16x8 contiguously (1KB)
__device__ __forceinline__ f16x8 load_b_swz(const _Float16* __restrict__ W,
                                            int t, int kc, int lane) {
  return *(const f16x8*)(W + (((size_t)t * 3 + kc) * 64 + lane) * 8);
}

// ---------- one-time prep ----------

__global__ void convert_x_kernel(const float* __restrict__ x,
                                 _Float16* __restrict__ h, int total4) {
  int i = blockIdx.x * blockDim.x + threadIdx.x;
  if (i >= total4) return;
  float4 v = ((const float4*)x)[i];
  f16x4 o;
  o[0] = (_Float16)v.x; o[1] = (_Float16)v.y;
  o[2] = (_Float16)v.z; o[3] = (_Float16)v.w;
  *(f16x4*)(h + (size_t)i * 4) = o;
}

// W_x[r][k] = sum_c W_ih[r][c] * W_e[c][k]; bxe[r] = sum_c W_ih[r][c] * b_e[c]
__global__ void compute_wx_kernel(const float* __restrict__ Wih,
                                  const float* __restrict__ We,
                                  const float* __restrict__ be,
                                  float* __restrict__ Wx,
                                  float* __restrict__ bxe) {
  int idx = blockIdx.x * blockDim.x + threadIdx.x;
  if (idx < G3 * D) {
    int r = idx / D, k = idx - r * D;
    float acc = 0.f;
    for (int c = 0; c < D; ++c) acc += Wih[r * D + c] * We[c * D + k];
    Wx[idx] = acc;
  } else if (idx < G3 * D + G3) {
    int r = idx - G3 * D;
    float acc = 0.f;
    for (int c = 0; c < D; ++c) acc += Wih[r * D + c] * be[c];
    bxe[r] = acc;
  }
}

// convert Wx/Whh to fp16 in MFMA-fragment (swizzled) order
__global__ void swizzle_f16_kernel(const float* __restrict__ Wx,
                                   const float* __restrict__ Whh,
                                   _Float16* __restrict__ WxF,
                                   _Float16* __restrict__ WhhF) {
  int idx = blockIdx.x * blockDim.x + threadIdx.x;
  if (idx >= 2 * NT * 3 * 64) return;
  int mat = idx / (NT * 3 * 64);
  int rem = idx - mat * (NT * 3 * 64);
  int t = rem / (3 * 64);
  int rem2 = rem - t * (3 * 64);
  int kc = rem2 >> 6;
  int lane = rem2 & 63;
  int c = t * 16 + (lane & 15);
  int k0 = kc * 32 + ((lane >> 4) << 3);
  const float* W = mat ? Whh : Wx;
  _Float16* dF = mat ? WhhF : WxF;
  f16x8 o;
#pragma unroll
  for (int j = 0; j < 8; ++j) o[j] = (_Float16)W[(size_t)c * D + k0 + j];
  *(f16x8*)(dF + (((size_t)t * 3 + kc) * 64 + lane) * 8) = o;
}

// ---------- CSR build ----------

__global__ void hist_kernel(const int* __restrict__ dst, int* __restrict__ counts, int E) {
  int e = blockIdx.x * blockDim.x + threadIdx.x;
  if (e < E) atomicAdd(&counts[dst[e]], 1);
}

__global__ void partial_sum_kernel(const int* __restrict__ counts,
                                   int* __restrict__ blk_sums, int n) {
  __shared__ int red[256];
  int base = blockIdx.x * SCAN_BLK;
  int tid = threadIdx.x;
  int s = 0;
#pragma unroll
  for (int j = 0; j < 4; ++j) {
    int i = base + j * 256 + tid;
    if (i < n) s += counts[i];
  }
  red[tid] = s;
  __syncthreads();
  for (int off = 128; off > 0; off >>= 1) {
    if (tid < off) red[tid] += red[tid + off];
    __syncthreads();
  }
  if (tid == 0) blk_sums[blockIdx.x] = red[0];
}

__global__ void scan_offsets_kernel(const int* __restrict__ blk_sums,
                                    int* __restrict__ blk_off,
                                    int* __restrict__ row_ptr, int nb, int n) {
  __shared__ int lds[64];
  int tid = threadIdx.x;
  if (tid < nb) lds[tid] = blk_sums[tid];
  __syncthreads();
  if (tid == 0) {
    int run = 0;
    for (int i = 0; i < nb; ++i) { blk_off[i] = run; run += lds[i]; }
    row_ptr[n] = run;
  }
}

__global__ void block_scan_kernel(const int* __restrict__ counts,
                                  const int* __restrict__ blk_off,
                                  int* __restrict__ row_ptr, int n) {
  __shared__ int red[256];
  int base = blockIdx.x * SCAN_BLK;
  int tid = threadIdx.x;
  int i0 = base + tid * 4;
  int v0 = 0, v1 = 0, v2 = 0, v3 = 0;
  if (i0 + 3 < n) {
    int4 c = *(const int4*)(counts + i0);
    v0 = c.x; v1 = c.y; v2 = c.z; v3 = c.w;
  } else {
    if (i0 < n) v0 = counts[i0];
    if (i0 + 1 < n) v1 = counts[i0 + 1];
    if (i0 + 2 < n) v2 = counts[i0 + 2];
  }
  int tsum = v0 + v1 + v2 + v3;
  red[tid] = tsum;
  __syncthreads();
  for (int off = 1; off < 256; off <<= 1) {
    int t = (tid >= off) ? red[tid - off] : 0;
    __syncthreads();
    red[tid] += t;
    __syncthreads();
  }
  int excl = blk_off[blockIdx.x] + red[tid] - tsum;
  if (i0 < n) row_ptr[i0] = excl;
  if (i0 + 1 < n) row_ptr[i0 + 1] = excl + v0;
  if (i0 + 2 < n) row_ptr[i0 + 2] = excl + v0 + v1;
  if (i0 + 3 < n) row_ptr[i0 + 3] = excl + v0 + v1 + v2;
}

__global__ void fill_kernel(const int* __restrict__ src, const int* __restrict__ dst,
                            const int* __restrict__ row_ptr,
                            int* __restrict__ fillc, int* __restrict__ csr_src, int E) {
  int e = blockIdx.x * blockDim.x + threadIdx.x;
  if (e >= E) return;
  int t = dst[e];
  int pos = row_ptr[t] + atomicAdd(&fillc[t], 1);
  csr_src[pos] = src[e];   // plain store (nontemporal regressed: R9 WRITE 55->65MB)
}

// ---------- fused per-step kernel ----------

// elementwise GRU epilogue over one 16-row tile staged in padded LDS planes
__device__ __forceinline__ void gru_epilogue(const float* lds,
                                             const _Float16* __restrict__ h,
                                             _Float16* __restrict__ hout,
                                             const int* __restrict__ row_ptr,
                                             const float* __restrict__ bxe,
                                             const float* __restrict__ bih,
                                             const float* __restrict__ bhh,
                                             int base_row, int tid) {
#pragma unroll
  for (int j = 0; j < 4; ++j) {
    int e = tid + j * 384;
    int row = e / D;
    int col = e - row * D;
    int grow = base_row + row;
    int a = row * PLS + col;
    float degf = (float)(row_ptr[grow + 1] - row_ptr[grow]);
    float R  = lds[a] + lds[PLANE + a];
    float Z  = lds[2 * PLANE + a] + lds[3 * PLANE + a];
    float XN = lds[4 * PLANE + a];
    float HN = lds[5 * PLANE + a];
    float rg = 1.0f / (1.0f + __expf(-(R + bih[col] + bhh[col] + degf * bxe[col])));
    float zg = 1.0f / (1.0f + __expf(-(Z + bih[D + col] + bhh[D + col] + degf * bxe[D + col])));
    float ng = tanhf(XN + bih[2 * D + col] + degf * bxe[2 * D + col] + rg * (HN + bhh[2 * D + col]));
    float hv = (float)h[(size_t)grow * D + col];
    hout[(size_t)grow * D + col] = (_Float16)((1.0f - zg) * ng + zg * hv);
  }
}

// Fused aggregate + GRU. Block = 32 rows, 6 waves (384 threads).
// Phase 1: 32 rows x 12 threads gather neighbor sums (f16x8 loads, fp32 accum).
// Phase 2: 6-way GEMM split: w0/w1/w2 = R_s/Z_s/XN (s from LDS);
//          w3/w4/w5 = R_h/Z_h/HN (h from global). 6 col-tiles each, 2 row-tiles.
// Phase 3: two-pass padded-plane epilogue.
__global__ __launch_bounds__(384) void gru_fused_kernel(
    const _Float16* __restrict__ h, _Float16* __restrict__ hout,
    const int* __restrict__ row_ptr, const int* __restrict__ csr_src,
    const _Float16* __restrict__ WxF, const _Float16* __restrict__ WhhF,
    const float* __restrict__ bxe, const float* __restrict__ bih,
    const float* __restrict__ bhh, int n) {
  __shared__ float lds[6 * PLANE];           // 37.2 KB gate planes (padded)
  __shared__ _Float16 sl[32][SLP];           // 6.7 KB aggregated s tile
  int r0 = blockIdx.x << 5;   // 32 rows per block
  int tid = threadIdx.x;
  int w = tid >> 6;
  int lane = tid & 63;

  // ---- phase 1: gather (12 threads/row, one f16x8 chunk each) ----
  {
    int row = tid / 12;        // 0..31
    int part = tid - row * 12; // chunk of 8 fp16
    int grow = r0 + row;
    float acc[8];
#pragma unroll
    for (int j = 0; j < 8; ++j) acc[j] = 0.f;
    if (grow < n) {
      int beg = row_ptr[grow], end = row_ptr[grow + 1];
      int e = beg;
      for (; e + 3 < end; e += 4) {
        int s0 = csr_src[e], s1 = csr_src[e + 1], s2 = csr_src[e + 2], s3 = csr_src[e + 3];
        f16x8 v0 = *(const f16x8*)(h + (size_t)s0 * D + part * 8);
        f16x8 v1 = *(const f16x8*)(h + (size_t)s1 * D + part * 8);
        f16x8 v2 = *(const f16x8*)(h + (size_t)s2 * D + part * 8);
        f16x8 v3 = *(const f16x8*)(h + (size_t)s3 * D + part * 8);
#pragma unroll
        for (int j = 0; j < 8; ++j)
          acc[j] += ((float)v0[j] + (float)v1[j]) + ((float)v2[j] + (float)v3[j]);
      }
      for (; e < end; ++e) {
        f16x8 v = *(const f16x8*)(h + (size_t)csr_src[e] * D + part * 8);
#pragma unroll
        for (int j = 0; j < 8; ++j) acc[j] += (float)v[j];
      }
    }
    f16x8 o;
#pragma unroll
    for (int j = 0; j < 8; ++j) o[j] = (_Float16)acc[j];
    *(f16x8*)&sl[row][part * 8] = o;
  }
  __syncthreads();

  // ---- phase 2: GEMM, 6-way split ----
  const int opS = (w < 3) ? 1 : 0;
  const _Float16* WF = opS ? WxF : WhhF;
  const int wg = opS ? w : (w - 3);        // 0=R, 1=Z, 2=N
  const int t0 = wg * 6;                   // col-tiles t0..t0+5
  const int plane = wg * 2 + (opS ? 0 : 1);

  f16x8 a0[3], a1[3];
  if (opS) {
#pragma unroll
    for (int kc = 0; kc < 3; ++kc) {
      int k0 = kc * 32 + ((lane >> 4) << 3);
      a0[kc] = *(const f16x8*)&sl[lane & 15][k0];
      a1[kc] = *(const f16x8*)&sl[16 + (lane & 15)][k0];
    }
  } else {
#pragma unroll
    for (int kc = 0; kc < 3; ++kc) {
      a0[kc] = load_a_frag(h, r0, lane, kc);
      a1[kc] = load_a_frag(h, r0 + 16, lane, kc);
    }
  }

  f32x4 acc0[6], acc1[6];
#pragma unroll
  for (int t = 0; t < 6; ++t) {
    acc0[t] = (f32x4){0.f, 0.f, 0.f, 0.f};
    acc1[t] = (f32x4){0.f, 0.f, 0.f, 0.f};
  }

#pragma unroll
  for (int ct = 0; ct < 6; ++ct)
#pragma unroll
    for (int kc = 0; kc < 3; ++kc) {
      f16x8 b = load_b_swz(WF, t0 + ct, kc, lane);
      acc0[ct] = __builtin_amdgcn_mfma_f32_16x16x32_f16(a0[kc], b, acc0[ct], 0, 0, 0);
      acc1[ct] = __builtin_amdgcn_mfma_f32_16x16x32_f16(a1[kc], b, acc1[ct], 0, 0, 0);
    }

  // ---- phase 3: epilogues (C/D layout: col=lane&15, row=(lane>>4)*4+q) ----
  int col_l = lane & 15;
  int rq = (lane >> 4) << 2;
#pragma unroll
  for (int ct = 0; ct < 6; ++ct)
#pragma unroll
    for (int q = 0; q < 4; ++q)
      lds[plane * PLANE + (rq + q) * PLS + ct * 16 + col_l] = acc0[ct][q];
  __syncthreads();
  gru_epilogue(lds, h, hout, row_ptr, bxe, bih, bhh, r0, tid);
  __syncthreads();
  if (r0 + 16 < n) {
#pragma unroll
    for (int ct = 0; ct < 6; ++ct)
#pragma unroll
      for (int q = 0; q < 4; ++q)
        lds[plane * PLANE + (rq + q) * PLS + ct * 16 + col_l] = acc1[ct][q];
    __syncthreads();
    gru_epilogue(lds, h, hout, row_ptr, bxe, bih, bhh, r0 + 16, tid);
  }
}

// logits[i,c] = sum_k elu(h[i,k]) * Wfc[c,k] + bfc[c]
__global__ void head_kernel(const _Float16* __restrict__ h,
                            const float* __restrict__ Wfc,
                            const float* __restrict__ bfc,
                            float* __restrict__ out,
                            int n, int C) {
  int idx = blockIdx.x * blockDim.x + threadIdx.x;
  if (idx >= n * C) return;
  int i = idx / C;
  int c = idx - i * C;
  const _Float16* hr = h + (size_t)i * D;
  const float* wr = Wfc + (size_t)c * D;
  float acc = bfc[c];
#pragma unroll 8
  for (int k = 0; k < D; ++k) {
    float hv = (float)hr[k];
    float e = hv > 0.0f ? hv : (__expf(hv) - 1.0f);
    acc += e * wr[k];
  }
  out[idx] = acc;
}

extern "C" void kernel_launch(void* const* d_in, const int* in_sizes, int n_in,
                              void* d_out, int out_size, void* d_ws, size_t ws_size,
                              hipStream_t stream) {
  const float* x    = (const float*)d_in[0];
  const int*   src  = (const int*)d_in[1];
  const int*   dst  = (const int*)d_in[2];
  const float* W_e  = (const float*)d_in[3];
  const float* b_e  = (const float*)d_in[4];
  const float* W_ih = (const float*)d_in[5];
  const float* W_hh = (const float*)d_in[6];
  const float* b_ih = (const float*)d_in[7];
  const float* b_hh = (const float*)d_in[8];
  const float* W_fc = (const float*)d_in[9];
  const float* b_fc = (const float*)d_in[10];

  const int n = in_sizes[0] / D;   // 50000
  const int E = in_sizes[1];       // 800000
  const int C = out_size / n;      // 10

  // ws layout (fp16 state):
  _Float16* hA = (_Float16*)d_ws;                 // n*D fp16
  _Float16* hB = hA + (size_t)n * D;              // n*D fp16
  float* Wx    = (float*)(hB + (size_t)n * D);    // G3*D fp32 temp
  _Float16* WxF  = (_Float16*)(Wx + (size_t)G3 * D);  // G3*D fp16 swizzled
  _Float16* WhhF = WxF + (size_t)G3 * D;
  float* bxe   = (float*)(WhhF + (size_t)G3 * D); // G3 fp32
  int* counts  = (int*)(bxe + G3);                // n
  int* fillc   = counts + n;                      // n
  int* row_ptr = fillc + n;                       // n+1
  int* csr_src = row_ptr + (n + 1);               // E
  int* blk_sums = csr_src + E;                    // <=64
  int* blk_off  = blk_sums + 64;                  // <=64

  const int threads = 256;
  const int nb = (n + SCAN_BLK - 1) / SCAN_BLK;

  (void)hipMemsetAsync(counts, 0, (size_t)2 * n * sizeof(int), stream);
  hist_kernel<<<(E + threads - 1) / threads, threads, 0, stream>>>(dst, counts, E);
  partial_sum_kernel<<<nb, 256, 0, stream>>>(counts, blk_sums, n);
  scan_offsets_kernel<<<1, 64, 0, stream>>>(blk_sums, blk_off, row_ptr, nb, n);
  block_scan_kernel<<<nb, 256, 0, stream>>>(counts, blk_off, row_ptr, n);
  fill_kernel<<<(E + threads - 1) / threads, threads, 0, stream>>>(src, dst, row_ptr,
                                                                   fillc, csr_src, E);
  compute_wx_kernel<<<(G3 * D + G3 + threads - 1) / threads, threads, 0, stream>>>(
      W_ih, W_e, b_e, Wx, bxe);
  swizzle_f16_kernel<<<(2 * NT * 3 * 64 + threads - 1) / threads, threads, 0, stream>>>(
      Wx, W_hh, WxF, WhhF);
  convert_x_kernel<<<((n * D / 4) + threads - 1) / threads, threads, 0, stream>>>(
      x, hA, n * D / 4);

  const int gridG = (n + 31) / 32;   // 32 rows per block

  const _Float16* hcur = hA;
  _Float16* hnext = hB;
  for (int step = 0; step < NSTEPS; ++step) {
    gru_fused_kernel<<<gridG, 384, 0, stream>>>(hcur, hnext, row_ptr, csr_src,
                                                WxF, WhhF, bxe, b_ih, b_hh, n);
    const _Float16* t = hcur; hcur = hnext; hnext = (_Float16*)t;
  }

  const int gridH = (n * C + threads - 1) / threads;
  head_kernel<<<gridH, threads, 0, stream>>>(hcur, W_fc, b_fc, (float*)d_out, n, C);
}

// Round 12
// 348.111 us; speedup vs baseline: 30.8078x; 1.0235x over previous
//
#include <hip/hip_runtime.h>

static constexpr int D = 96;       // hidden size
static constexpr int G3 = 3 * D;   // 288 gate rows
static constexpr int NSTEPS = 4;   // GGNN propagation steps
static constexpr int NT = 18;      // 288/16 col-tiles per weight matrix
static constexpr int SCAN_BLK = 1024;  // elements per scan block
static constexpr int SLP = 104;    // s-tile LDS row pad (fp16)
static constexpr int PLS = 97;     // plane row stride (dwords)
static constexpr int PLANE = 16 * PLS;

typedef __attribute__((ext_vector_type(8))) _Float16 f16x8;  // 8 fp16 (4 VGPRs)
typedef __attribute__((ext_vector_type(4))) _Float16 f16x4;
typedef __attribute__((ext_vector_type(4))) float f32x4;     // MFMA C/D frag

// A-fragment for mfma_f32_16x16x32_f16 from fp16 row-major [*,96]:
// lane holds row=r0+(lane&15), k = kc*32 + (lane>>4)*8 .. +7 -> 16B contiguous
__device__ __forceinline__ f16x8 load_a_frag(const _Float16* __restrict__ base,
                                             int r0, int lane, int kc) {
  int row = r0 + (lane & 15);
  int k0 = kc * 32 + ((lane >> 4) << 3);
  return *(const f16x8*)(base + (size_t)row * D + k0);
}

// Swizzled B-fragment: slot (t,kc) holds 64 lanes' f16x8 contiguously (1KB)
__device__ __forceinline__ f16x8 load_b_swz(const _Float16* __restrict__ W,
                                            int t, int kc, int lane) {
  return *(const f16x8*)(W + (((size_t)t * 3 + kc) * 64 + lane) * 8);
}

// ---------- one-time prep ----------

__global__ void convert_x_kernel(const float* __restrict__ x,
                                 _Float16* __restrict__ h, int total4) {
  int i = blockIdx.x * blockDim.x + threadIdx.x;
  if (i >= total4) return;
  float4 v = ((const float4*)x)[i];
  f16x4 o;
  o[0] = (_Float16)v.x; o[1] = (_Float16)v.y;
  o[2] = (_Float16)v.z; o[3] = (_Float16)v.w;
  *(f16x4*)(h + (size_t)i * 4) = o;
}

// W_x[r][k] = sum_c W_ih[r][c] * W_e[c][k]; bxe[r] = sum_c W_ih[r][c] * b_e[c]
__global__ void compute_wx_kernel(const float* __restrict__ Wih,
                                  const float* __restrict__ We,
                                  const float* __restrict__ be,
                                  float* __restrict__ Wx,
                                  float* __restrict__ bxe) {
  int idx = blockIdx.x * blockDim.x + threadIdx.x;
  if (idx < G3 * D) {
    int r = idx / D, k = idx - r * D;
    float acc = 0.f;
    for (int c = 0; c < D; ++c) acc += Wih[r * D + c] * We[c * D + k];
    Wx[idx] = acc;
  } else if (idx < G3 * D + G3) {
    int r = idx - G3 * D;
    float acc = 0.f;
    for (int c = 0; c < D; ++c) acc += Wih[r * D + c] * be[c];
    bxe[r] = acc;
  }
}

// convert Wx/Whh to fp16 in MFMA-fragment (swizzled) order
__global__ void swizzle_f16_kernel(const float* __restrict__ Wx,
                                   const float* __restrict__ Whh,
                                   _Float16* __restrict__ WxF,
                                   _Float16* __restrict__ WhhF) {
  int idx = blockIdx.x * blockDim.x + threadIdx.x;
  if (idx >= 2 * NT * 3 * 64) return;
  int mat = idx / (NT * 3 * 64);
  int rem = idx - mat * (NT * 3 * 64);
  int t = rem / (3 * 64);
  int rem2 = rem - t * (3 * 64);
  int kc = rem2 >> 6;
  int lane = rem2 & 63;
  int c = t * 16 + (lane & 15);
  int k0 = kc * 32 + ((lane >> 4) << 3);
  const float* W = mat ? Whh : Wx;
  _Float16* dF = mat ? WhhF : WxF;
  f16x8 o;
#pragma unroll
  for (int j = 0; j < 8; ++j) o[j] = (_Float16)W[(size_t)c * D + k0 + j];
  *(f16x8*)(dF + (((size_t)t * 3 + kc) * 64 + lane) * 8) = o;
}

// ---------- CSR build ----------

__global__ void hist_kernel(const int* __restrict__ dst, int* __restrict__ counts, int E) {
  int e = blockIdx.x * blockDim.x + threadIdx.x;
  if (e < E) atomicAdd(&counts[dst[e]], 1);
}

__global__ void partial_sum_kernel(const int* __restrict__ counts,
                                   int* __restrict__ blk_sums, int n) {
  __shared__ int red[256];
  int base = blockIdx.x * SCAN_BLK;
  int tid = threadIdx.x;
  int s = 0;
#pragma unroll
  for (int j = 0; j < 4; ++j) {
    int i = base + j * 256 + tid;
    if (i < n) s += counts[i];
  }
  red[tid] = s;
  __syncthreads();
  for (int off = 128; off > 0; off >>= 1) {
    if (tid < off) red[tid] += red[tid + off];
    __syncthreads();
  }
  if (tid == 0) blk_sums[blockIdx.x] = red[0];
}

__global__ void scan_offsets_kernel(const int* __restrict__ blk_sums,
                                    int* __restrict__ blk_off,
                                    int* __restrict__ row_ptr, int nb, int n) {
  __shared__ int lds[64];
  int tid = threadIdx.x;
  if (tid < nb) lds[tid] = blk_sums[tid];
  __syncthreads();
  if (tid == 0) {
    int run = 0;
    for (int i = 0; i < nb; ++i) { blk_off[i] = run; run += lds[i]; }
    row_ptr[n] = run;
  }
}

__global__ void block_scan_kernel(const int* __restrict__ counts,
                                  const int* __restrict__ blk_off,
                                  int* __restrict__ row_ptr, int n) {
  __shared__ int red[256];
  int base = blockIdx.x * SCAN_BLK;
  int tid = threadIdx.x;
  int i0 = base + tid * 4;
  int v0 = 0, v1 = 0, v2 = 0, v3 = 0;
  if (i0 + 3 < n) {
    int4 c = *(const int4*)(counts + i0);
    v0 = c.x; v1 = c.y; v2 = c.z; v3 = c.w;
  } else {
    if (i0 < n) v0 = counts[i0];
    if (i0 + 1 < n) v1 = counts[i0 + 1];
    if (i0 + 2 < n) v2 = counts[i0 + 2];
  }
  int tsum = v0 + v1 + v2 + v3;
  red[tid] = tsum;
  __syncthreads();
  for (int off = 1; off < 256; off <<= 1) {
    int t = (tid >= off) ? red[tid - off] : 0;
    __syncthreads();
    red[tid] += t;
    __syncthreads();
  }
  int excl = blk_off[blockIdx.x] + red[tid] - tsum;
  if (i0 < n) row_ptr[i0] = excl;
  if (i0 + 1 < n) row_ptr[i0 + 1] = excl + v0;
  if (i0 + 2 < n) row_ptr[i0 + 2] = excl + v0 + v1;
  if (i0 + 3 < n) row_ptr[i0 + 3] = excl + v0 + v1 + v2;
}

// csr_src stored as uint16 (n < 65536): halves scatter-write traffic
__global__ void fill_kernel(const int* __restrict__ src, const int* __restrict__ dst,
                            const int* __restrict__ row_ptr,
                            int* __restrict__ fillc,
                            unsigned short* __restrict__ csr_src, int E) {
  int e = blockIdx.x * blockDim.x + threadIdx.x;
  if (e >= E) return;
  int t = dst[e];
  int pos = row_ptr[t] + atomicAdd(&fillc[t], 1);
  csr_src[pos] = (unsigned short)src[e];
}

// ---------- fused per-step kernel ----------

// elementwise GRU epilogue over one 16-row tile staged in padded LDS planes
__device__ __forceinline__ void gru_epilogue(const float* lds,
                                             const _Float16* __restrict__ h,
                                             _Float16* __restrict__ hout,
                                             const int* __restrict__ row_ptr,
                                             const float* __restrict__ bxe,
                                             const float* __restrict__ bih,
                                             const float* __restrict__ bhh,
                                             int base_row, int tid) {
#pragma unroll
  for (int j = 0; j < 4; ++j) {
    int e = tid + j * 384;
    int row = e / D;
    int col = e - row * D;
    int grow = base_row + row;
    int a = row * PLS + col;
    float degf = (float)(row_ptr[grow + 1] - row_ptr[grow]);
    float R  = lds[a] + lds[PLANE + a];
    float Z  = lds[2 * PLANE + a] + lds[3 * PLANE + a];
    float XN = lds[4 * PLANE + a];
    float HN = lds[5 * PLANE + a];
    float rg = 1.0f / (1.0f + __expf(-(R + bih[col] + bhh[col] + degf * bxe[col])));
    float zg = 1.0f / (1.0f + __expf(-(Z + bih[D + col] + bhh[D + col] + degf * bxe[D + col])));
    float ng = tanhf(XN + bih[2 * D + col] + degf * bxe[2 * D + col] + rg * (HN + bhh[2 * D + col]));
    float hv = (float)h[(size_t)grow * D + col];
    hout[(size_t)grow * D + col] = (_Float16)((1.0f - zg) * ng + zg * hv);
  }
}

// Fused aggregate + GRU. Block = 32 rows, 6 waves (384 threads).
// LDS: 6 padded planes (37.2 KB); s-tile ALIASES planes 4/5 (freed before phase 3)
// -> 4 blocks/CU.
__global__ __launch_bounds__(384) void gru_fused_kernel(
    const _Float16* __restrict__ h, _Float16* __restrict__ hout,
    const int* __restrict__ row_ptr, const unsigned short* __restrict__ csr_src,
    const _Float16* __restrict__ WxF, const _Float16* __restrict__ WhhF,
    const float* __restrict__ bxe, const float* __restrict__ bih,
    const float* __restrict__ bhh, int n) {
  __shared__ float lds[6 * PLANE];                    // 37.2 KB total
  _Float16* sl = (_Float16*)&lds[4 * PLANE];          // s tile aliases planes 4/5
  int r0 = blockIdx.x << 5;   // 32 rows per block
  int tid = threadIdx.x;
  int w = tid >> 6;
  int lane = tid & 63;

  // ---- phase 1: gather (12 threads/row, one f16x8 chunk each; 8-deep MLP) ----
  {
    int row = tid / 12;        // 0..31
    int part = tid - row * 12; // chunk of 8 fp16
    int grow = r0 + row;
    float acc[8];
#pragma unroll
    for (int j = 0; j < 8; ++j) acc[j] = 0.f;
    if (grow < n) {
      int beg = row_ptr[grow], end = row_ptr[grow + 1];
      const _Float16* hp = h + (size_t)part * 8;
      int e = beg;
      for (; e + 7 < end; e += 8) {
        f16x8 v0 = *(const f16x8*)(hp + (size_t)csr_src[e] * D);
        f16x8 v1 = *(const f16x8*)(hp + (size_t)csr_src[e + 1] * D);
        f16x8 v2 = *(const f16x8*)(hp + (size_t)csr_src[e + 2] * D);
        f16x8 v3 = *(const f16x8*)(hp + (size_t)csr_src[e + 3] * D);
        f16x8 v4 = *(const f16x8*)(hp + (size_t)csr_src[e + 4] * D);
        f16x8 v5 = *(const f16x8*)(hp + (size_t)csr_src[e + 5] * D);
        f16x8 v6 = *(const f16x8*)(hp + (size_t)csr_src[e + 6] * D);
        f16x8 v7 = *(const f16x8*)(hp + (size_t)csr_src[e + 7] * D);
#pragma unroll
        for (int j = 0; j < 8; ++j)
          acc[j] += (((float)v0[j] + (float)v1[j]) + ((float)v2[j] + (float)v3[j])) +
                    (((float)v4[j] + (float)v5[j]) + ((float)v6[j] + (float)v7[j]));
      }
      if (e + 3 < end) {
        f16x8 v0 = *(const f16x8*)(hp + (size_t)csr_src[e] * D);
        f16x8 v1 = *(const f16x8*)(hp + (size_t)csr_src[e + 1] * D);
        f16x8 v2 = *(const f16x8*)(hp + (size_t)csr_src[e + 2] * D);
        f16x8 v3 = *(const f16x8*)(hp + (size_t)csr_src[e + 3] * D);
#pragma unroll
        for (int j = 0; j < 8; ++j)
          acc[j] += ((float)v0[j] + (float)v1[j]) + ((float)v2[j] + (float)v3[j]);
        e += 4;
      }
      for (; e < end; ++e) {
        f16x8 v = *(const f16x8*)(hp + (size_t)csr_src[e] * D);
#pragma unroll
        for (int j = 0; j < 8; ++j) acc[j] += (float)v[j];
      }
    }
    f16x8 o;
#pragma unroll
    for (int j = 0; j < 8; ++j) o[j] = (_Float16)acc[j];
    *(f16x8*)&sl[row * SLP + part * 8] = o;
  }
  __syncthreads();

  // ---- phase 2: A-fragment loads ----
  const int opS = (w < 3) ? 1 : 0;
  const _Float16* WF = opS ? WxF : WhhF;
  const int wg = opS ? w : (w - 3);        // 0=R, 1=Z, 2=N
  const int t0 = wg * 6;                   // col-tiles t0..t0+5
  const int plane = wg * 2 + (opS ? 0 : 1);

  f16x8 a0[3], a1[3];
  if (opS) {
#pragma unroll
    for (int kc = 0; kc < 3; ++kc) {
      int k0 = kc * 32 + ((lane >> 4) << 3);
      a0[kc] = *(const f16x8*)&sl[(lane & 15) * SLP + k0];
      a1[kc] = *(const f16x8*)&sl[(16 + (lane & 15)) * SLP + k0];
    }
  } else {
#pragma unroll
    for (int kc = 0; kc < 3; ++kc) {
      a0[kc] = load_a_frag(h, r0, lane, kc);
      a1[kc] = load_a_frag(h, r0 + 16, lane, kc);
    }
  }
  __syncthreads();   // sl fully read (in regs) before planes 4/5 are overwritten

  f32x4 acc0[6], acc1[6];
#pragma unroll
  for (int t = 0; t < 6; ++t) {
    acc0[t] = (f32x4){0.f, 0.f, 0.f, 0.f};
    acc1[t] = (f32x4){0.f, 0.f, 0.f, 0.f};
  }

#pragma unroll
  for (int ct = 0; ct < 6; ++ct)
#pragma unroll
    for (int kc = 0; kc < 3; ++kc) {
      f16x8 b = load_b_swz(WF, t0 + ct, kc, lane);
      acc0[ct] = __builtin_amdgcn_mfma_f32_16x16x32_f16(a0[kc], b, acc0[ct], 0, 0, 0);
      acc1[ct] = __builtin_amdgcn_mfma_f32_16x16x32_f16(a1[kc], b, acc1[ct], 0, 0, 0);
    }

  // ---- phase 3: epilogues (C/D layout: col=lane&15, row=(lane>>4)*4+q) ----
  int col_l = lane & 15;
  int rq = (lane >> 4) << 2;
#pragma unroll
  for (int ct = 0; ct < 6; ++ct)
#pragma unroll
    for (int q = 0; q < 4; ++q)
      lds[plane * PLANE + (rq + q) * PLS + ct * 16 + col_l] = acc0[ct][q];
  __syncthreads();
  gru_epilogue(lds, h, hout, row_ptr, bxe, bih, bhh, r0, tid);
  __syncthreads();
  if (r0 + 16 < n) {
#pragma unroll
    for (int ct = 0; ct < 6; ++ct)
#pragma unroll
      for (int q = 0; q < 4; ++q)
        lds[plane * PLANE + (rq + q) * PLS + ct * 16 + col_l] = acc1[ct][q];
    __syncthreads();
    gru_epilogue(lds, h, hout, row_ptr, bxe, bih, bhh, r0 + 16, tid);
  }
}

// logits[i,c] = sum_k elu(h[i,k]) * Wfc[c,k] + bfc[c]
__global__ void head_kernel(const _Float16* __restrict__ h,
                            const float* __restrict__ Wfc,
                            const float* __restrict__ bfc,
                            float* __restrict__ out,
                            int n, int C) {
  int idx = blockIdx.x * blockDim.x + threadIdx.x;
  if (idx >= n * C) return;
  int i = idx / C;
  int c = idx - i * C;
  const _Float16* hr = h + (size_t)i * D;
  const float* wr = Wfc + (size_t)c * D;
  float acc = bfc[c];
#pragma unroll 8
  for (int k = 0; k < D; ++k) {
    float hv = (float)hr[k];
    float e = hv > 0.0f ? hv : (__expf(hv) - 1.0f);
    acc += e * wr[k];
  }
  out[idx] = acc;
}

extern "C" void kernel_launch(void* const* d_in, const int* in_sizes, int n_in,
                              void* d_out, int out_size, void* d_ws, size_t ws_size,
                              hipStream_t stream) {
  const float* x    = (const float*)d_in[0];
  const int*   src  = (const int*)d_in[1];
  const int*   dst  = (const int*)d_in[2];
  const float* W_e  = (const float*)d_in[3];
  const float* b_e  = (const float*)d_in[4];
  const float* W_ih = (const float*)d_in[5];
  const float* W_hh = (const float*)d_in[6];
  const float* b_ih = (const float*)d_in[7];
  const float* b_hh = (const float*)d_in[8];
  const float* W_fc = (const float*)d_in[9];
  const float* b_fc = (const float*)d_in[10];

  const int n = in_sizes[0] / D;   // 50000
  const int E = in_sizes[1];       // 800000
  const int C = out_size / n;      // 10

  // ws layout (fp16 state):
  _Float16* hA = (_Float16*)d_ws;                 // n*D fp16
  _Float16* hB = hA + (size_t)n * D;              // n*D fp16
  float* Wx    = (float*)(hB + (size_t)n * D);    // G3*D fp32 temp
  _Float16* WxF  = (_Float16*)(Wx + (size_t)G3 * D);  // G3*D fp16 swizzled
  _Float16* WhhF = WxF + (size_t)G3 * D;
  float* bxe   = (float*)(WhhF + (size_t)G3 * D); // G3 fp32
  int* counts  = (int*)(bxe + G3);                // n
  int* fillc   = counts + n;                      // n
  int* row_ptr = fillc + n;                       // n+1
  unsigned short* csr_src = (unsigned short*)(row_ptr + (n + 1));  // E u16
  int* blk_sums = (int*)(csr_src + E);            // <=64  (E even -> aligned)
  int* blk_off  = blk_sums + 64;                  // <=64

  const int threads = 256;
  const int nb = (n + SCAN_BLK - 1) / SCAN_BLK;

  (void)hipMemsetAsync(counts, 0, (size_t)2 * n * sizeof(int), stream);
  hist_kernel<<<(E + threads - 1) / threads, threads, 0, stream>>>(dst, counts, E);
  partial_sum_kernel<<<nb, 256, 0, stream>>>(counts, blk_sums, n);
  scan_offsets_kernel<<<1, 64, 0, stream>>>(blk_sums, blk_off, row_ptr, nb, n);
  block_scan_kernel<<<nb, 256, 0, stream>>>(counts, blk_off, row_ptr, n);
  fill_kernel<<<(E + threads - 1) / threads, threads, 0, stream>>>(src, dst, row_ptr,
                                                                   fillc, csr_src, E);
  compute_wx_kernel<<<(G3 * D + G3 + threads - 1) / threads, threads, 0, stream>>>(
      W_ih, W_e, b_e, Wx, bxe);
  swizzle_f16_kernel<<<(2 * NT * 3 * 64 + threads - 1) / threads, threads, 0, stream>>>(
      Wx, W_hh, WxF, WhhF);
  convert_x_kernel<<<((n * D / 4) + threads - 1) / threads, threads, 0, stream>>>(
      x, hA, n * D / 4);

  const int gridG = (n + 31) / 32;   // 32 rows per block

  const _Float16* hcur = hA;
  _Float16* hnext = hB;
  for (int step = 0; step < NSTEPS; ++step) {
    gru_fused_kernel<<<gridG, 384, 0, stream>>>(hcur, hnext, row_ptr, csr_src,
                                                WxF, WhhF, bxe, b_ih, b_hh, n);
    const _Float16* t = hcur; hcur = hnext; hnext = (_Float16*)t;
  }

  const int gridH = (n * C + threads - 1) / threads;
  head_kernel<<<gridH, threads, 0, stream>>>(hcur, W_fc, b_fc, (float*)d_out, n, C);
}